// Round 7
// baseline (670.938 us; speedup 1.0000x reference)
//
#include <hip/hip_runtime.h>

// Problem sizes
#define NROWS 8192   // B*T
#define MCB   1024   // codebook size M
#define DD    256    // feature dim D
#define TT    128    // T
#define BB    64     // B

// ws offsets (in floats)
#define OFF_DA      0ul
#define OFF_DV      8388608ul
#define OFF_XX_A    16777216ul
#define OFF_XX_V    16785408ul
#define OFF_EE      16793600ul
#define OFF_SMIN_A  16794624ul
#define OFF_LZ1_A   16802816ul
#define OFF_IZ2_A   16811008ul
#define OFF_IDX_A   16819200ul
#define OFF_SMIN_V  16827392ul
#define OFF_LZ1_V   16835584ul
#define OFF_IZ2_V   16843776ul
#define OFF_IDX_V   16851968ul
#define OFF_S1      16860160ul
#define OFF_S2      17384448ul
#define OFF_PART    17908736ul
#define OFF_MAX     17908992ul
#define OFF_PACC    17909000ul   // 256 doubles, per-block loss partials

// ---------------------------------------------------------------------------
// Kernel 1: row sums of squares (fp64 accumulate for accuracy)
__global__ void k_sumsq(const float* __restrict__ A, const float* __restrict__ V,
                        const float* __restrict__ E, float* __restrict__ ws) {
  const int lane = threadIdx.x & 63;
  const int wid  = threadIdx.x >> 6;
  const int row = blockIdx.x * 4 + wid;   // 0..17407
  const float* src; float* dst; int r;
  if (row < 8192)       { src = A; r = row;         dst = ws + OFF_XX_A; }
  else if (row < 16384) { src = V; r = row - 8192;  dst = ws + OFF_XX_V; }
  else                  { src = E; r = row - 16384; dst = ws + OFF_EE; }
  float4 x = *(const float4*)(src + (size_t)r * DD + lane * 4);
  double acc = (double)x.x * x.x + (double)x.y * x.y +
               (double)x.z * x.z + (double)x.w * x.w;
  #pragma unroll
  for (int off = 32; off; off >>= 1) acc += __shfl_xor(acc, off);
  if (lane == 0) dst[r] = (float)acc;
}

// ---------------------------------------------------------------------------
// Kernel 2: dist GEMM. d[n,m] = (ee[m] + xx[n]) - 2 * (x[n,:] . e[m,:])
// 128x128 C-tile, 8x8/thread (0.5 B/FLOP -> LDS pipe at 50%), K-chunk 32,
// SINGLE 32 KB LDS buffer (occupancy ~3 blocks/CU) + T14 reg-staged prefetch:
// next chunk's global float4s issued into regs BEFORE compute, ds_write after
// the read-barrier. XOR swizzle key=(row>>3)&7 on the WRITE address and the
// same key on frag reads (both-sides-or-neither):
//   write: thread (rb=tid>>3 + 32i, cq=tid&7) -> addr r*32 + ((cq^key)<<2)
//   read:  idx = row*32 + (k4 ^ (((row>>3)&7)<<2))
// Per-16-lane-group bank-quad cover: writes 8 quads x2 (free), A-frag reads
// broadcast (free), B-frag reads 8 quads x2 (free).
__global__ __launch_bounds__(256) void k_dist(const float* __restrict__ A,
    const float* __restrict__ V, const float* __restrict__ E,
    float* __restrict__ ws) {
  const int z = blockIdx.z;
  const float* X  = z ? V : A;
  const float* xx = ws + (z ? OFF_XX_V : OFF_XX_A);
  const float* ee = ws + OFF_EE;
  float* Dst = ws + (z ? OFF_DV : OFF_DA);

  __shared__ __align__(16) float As[128 * 32];
  __shared__ __align__(16) float Bs[128 * 32];

  const int tid = threadIdx.x;
  const int tx = tid & 15;          // col group: cols tx*8..tx*8+7
  const int ty = tid >> 4;          // row group: rows ty*8..ty*8+7

  // chunked XCD swizzle (512 blocks per z, bijective)
  const int bid = blockIdx.y * 8 + blockIdx.x;        // 0..511
  const int sw  = (bid & 7) * 64 + (bid >> 3);
  const int colb = sw & 7, rowb = sw >> 3;
  const int row0 = rowb * 128;
  const int col0 = colb * 128;

  // staging assignment: logical k-quad cq, rows rb+32i
  const int cq = tid & 7;
  const int rb = tid >> 3;          // 0..31
  int wo[4]; const float* gA[4]; const float* gB[4];
  #pragma unroll
  for (int i = 0; i < 4; ++i) {
    int r = rb + 32 * i;
    int key = (r >> 3) & 7;
    wo[i] = r * 32 + ((cq ^ key) << 2);
    gA[i] = X + (size_t)(row0 + r) * DD + cq * 4;
    gB[i] = E + (size_t)(col0 + r) * DD + cq * 4;
  }

  const int xa = (ty & 7) << 2;
  const int xb = (tx & 7) << 2;

  float acc[8][8] = {};
  float4 pa[4], pb[4];

  // prologue: chunk 0 via regs
  #pragma unroll
  for (int i = 0; i < 4; ++i) { pa[i] = *(const float4*)(gA[i]); pb[i] = *(const float4*)(gB[i]); }
  #pragma unroll
  for (int i = 0; i < 4; ++i) { *(float4*)(&As[wo[i]]) = pa[i]; *(float4*)(&Bs[wo[i]]) = pb[i]; }
  __syncthreads();

  for (int t = 0; t < 8; ++t) {
    if (t < 7) {
      const int kc = (t + 1) * 32;
      #pragma unroll
      for (int i = 0; i < 4; ++i) {
        pa[i] = *(const float4*)(gA[i] + kc);
        pb[i] = *(const float4*)(gB[i] + kc);
      }
    }
    #pragma unroll
    for (int k4 = 0; k4 < 32; k4 += 4) {
      float4 a[8], b[8];
      #pragma unroll
      for (int i = 0; i < 8; ++i)
        a[i] = *(const float4*)(&As[(ty * 8 + i) * 32 + (k4 ^ xa)]);
      #pragma unroll
      for (int j = 0; j < 8; ++j)
        b[j] = *(const float4*)(&Bs[(tx * 8 + j) * 32 + (k4 ^ xb)]);
      #pragma unroll
      for (int i = 0; i < 8; ++i)
        #pragma unroll
        for (int j = 0; j < 8; ++j) {
          acc[i][j] = fmaf(a[i].x, b[j].x, acc[i][j]);
          acc[i][j] = fmaf(a[i].y, b[j].y, acc[i][j]);
          acc[i][j] = fmaf(a[i].z, b[j].z, acc[i][j]);
          acc[i][j] = fmaf(a[i].w, b[j].w, acc[i][j]);
        }
    }
    __syncthreads();          // all waves done reading current chunk
    if (t < 7) {
      #pragma unroll
      for (int i = 0; i < 4; ++i) { *(float4*)(&As[wo[i]]) = pa[i]; *(float4*)(&Bs[wo[i]]) = pb[i]; }
      __syncthreads();        // next chunk visible
    }
  }

  float er[8];
  #pragma unroll
  for (int j = 0; j < 8; ++j) er[j] = ee[col0 + tx * 8 + j];
  #pragma unroll
  for (int i = 0; i < 8; ++i) {
    float xri = xx[row0 + ty * 8 + i];
    float o[8];
    #pragma unroll
    for (int j = 0; j < 8; ++j) o[j] = (er[j] + xri) - 2.0f * acc[i][j];
    float* drow = Dst + (size_t)(row0 + ty * 8 + i) * MCB + col0 + tx * 8;
    *(float4*)(drow)     = *(const float4*)(&o[0]);
    *(float4*)(drow + 4) = *(const float4*)(&o[4]);
  }
}

// ---------------------------------------------------------------------------
// Kernel 3: per-row stats (min/argmin, softmax denominators) + quantize write.
__global__ void k_rowstats(const float* __restrict__ A, const float* __restrict__ V,
                           const float* __restrict__ E, float* __restrict__ ws,
                           float* __restrict__ out) {
  const int z = blockIdx.y;
  const float* Dm = ws + (z ? OFF_DV : OFF_DA);
  const float* X  = z ? V : A;
  float* smin_o = ws + (z ? OFF_SMIN_V : OFF_SMIN_A);
  float* lz1_o  = ws + (z ? OFF_LZ1_V  : OFF_LZ1_A);
  float* iz2_o  = ws + (z ? OFF_IZ2_V  : OFF_IZ2_A);
  int*   idx_o  = (int*)(ws + (z ? OFF_IDX_V : OFF_IDX_A));
  float* qout = out + 1 + (size_t)z * ((size_t)NROWS * DD);

  const int lane = threadIdx.x & 63, wid = threadIdx.x >> 6;
  const int n = blockIdx.x * 4 + wid;
  const float* drow = Dm + (size_t)n * MCB;

  float v[16];
  #pragma unroll
  for (int c = 0; c < 4; ++c) {
    float4 t = *(const float4*)(drow + c * 256 + lane * 4);
    v[c*4+0] = t.x; v[c*4+1] = t.y; v[c*4+2] = t.z; v[c*4+3] = t.w;
  }
  float bv = 3.4e38f; int bi = 0;
  #pragma unroll
  for (int c = 0; c < 4; ++c)
    #pragma unroll
    for (int j = 0; j < 4; ++j) {
      float val = v[c*4+j];
      int m = c * 256 + lane * 4 + j;
      if (val < bv) { bv = val; bi = m; }
    }
  #pragma unroll
  for (int off = 32; off; off >>= 1) {
    float ov = __shfl_xor(bv, off);
    int   oi = __shfl_xor(bi, off);
    if (ov < bv || (ov == bv && oi < bi)) { bv = ov; bi = oi; }
  }
  float smin = sqrtf(fmaxf(bv, 0.0f));
  float z1 = 0.f, z2 = 0.f;
  #pragma unroll
  for (int q = 0; q < 16; ++q) {
    float w = sqrtf(fmaxf(v[q], 0.0f)) - smin;
    z1 += expf(-w);
    z2 += expf(-2.0f * w);
  }
  #pragma unroll
  for (int off = 32; off; off >>= 1) {
    z1 += __shfl_xor(z1, off);
    z2 += __shfl_xor(z2, off);
  }
  if (lane == 0) {
    smin_o[n] = smin;
    lz1_o[n]  = logf(z1);
    iz2_o[n]  = 1.0f / z2;
    idx_o[n]  = bi;
  }
  const float* erow = E + (size_t)bi * DD;
  const float* xrow = X + (size_t)n * DD;
  #pragma unroll
  for (int p = 0; p < 4; ++p) {
    int d0 = p * 64 + lane;
    float xv = xrow[d0];
    float ev = erow[d0];
    qout[(size_t)n * DD + d0] = xv + (ev - xv);
  }
}

// ---------------------------------------------------------------------------
// Kernel 4: S[t,b,c] = sum_m adj_p[b*T+t, m] * logq[c*T+t, m]
__global__ __launch_bounds__(256) void k_sgemm(float* __restrict__ ws) {
  const int z = blockIdx.y;
  const int t = blockIdx.x;
  const float* Dp = ws + (z ? OFF_DV : OFF_DA);
  const float* Dq = ws + (z ? OFF_DA : OFF_DV);
  const float* smin_p = ws + (z ? OFF_SMIN_V : OFF_SMIN_A);
  const float* iz2_p  = ws + (z ? OFF_IZ2_V  : OFF_IZ2_A);
  const float* smin_q = ws + (z ? OFF_SMIN_A : OFF_SMIN_V);
  const float* lz1_q  = ws + (z ? OFF_LZ1_A  : OFF_LZ1_V);
  float* S = ws + (z ? OFF_S2 : OFF_S1);

  __shared__ __align__(16) float PA[64][68];
  __shared__ __align__(16) float LQ[64][68];
  __shared__ float sP[64], izP[64], sQ[64], lzQ[64];

  const int tid = threadIdx.x;
  const int tx = tid & 15, ty = tid >> 4;
  const int lm = tid & 63, wq = tid >> 6;

  if (tid < 64) {
    size_t n = (size_t)tid * TT + t;
    sP[tid] = smin_p[n]; izP[tid] = iz2_p[n];
    sQ[tid] = smin_q[n]; lzQ[tid] = lz1_q[n];
  }
  __syncthreads();

  float acc[4][4] = {};
  for (int mc = 0; mc < MCB; mc += 64) {
    #pragma unroll
    for (int i = 0; i < 16; ++i) {
      int b = i * 4 + wq;
      size_t n = (size_t)b * TT + t;
      float dp = Dp[n * MCB + mc + lm];
      float wp = sqrtf(fmaxf(dp, 0.f)) - sP[b];
      PA[lm][b] = expf(-2.f * wp) * izP[b];
      float dq = Dq[n * MCB + mc + lm];
      float wv = sqrtf(fmaxf(dq, 0.f)) - sQ[b];
      LQ[lm][b] = -wv - lzQ[b];
    }
    __syncthreads();
    #pragma unroll
    for (int mm = 0; mm < 64; ++mm) {
      float4 av = *(const float4*)(&PA[mm][ty << 2]);
      float4 bv = *(const float4*)(&LQ[mm][tx << 2]);
      float aa[4] = {av.x, av.y, av.z, av.w};
      float bb[4] = {bv.x, bv.y, bv.z, bv.w};
      #pragma unroll
      for (int i = 0; i < 4; ++i)
        #pragma unroll
        for (int j = 0; j < 4; ++j)
          acc[i][j] = fmaf(aa[i], bb[j], acc[i][j]);
    }
    __syncthreads();
  }
  #pragma unroll
  for (int i = 0; i < 4; ++i) {
    float4 o = {acc[i][0], acc[i][1], acc[i][2], acc[i][3]};
    *(float4*)(S + ((size_t)t * 64 + (ty << 2) + i) * 64 + (tx << 2)) = o;
  }
}

// ---------------------------------------------------------------------------
// Kernel 5a: partial min over S1/S2
__global__ void k_smin(float* __restrict__ ws) {
  const float* S = ws + (blockIdx.y ? OFF_S2 : OFF_S1);
  float* part = ws + OFF_PART;
  size_t base = (size_t)blockIdx.x * 4096;
  float m = 3.4e38f;
  for (int i = threadIdx.x; i < 4096; i += 256) m = fminf(m, S[base + i]);
  #pragma unroll
  for (int off = 32; off; off >>= 1) m = fminf(m, __shfl_xor(m, off));
  __shared__ float red[4];
  const int lane = threadIdx.x & 63, wid = threadIdx.x >> 6;
  if (lane == 0) red[wid] = m;
  __syncthreads();
  if (threadIdx.x == 0)
    part[blockIdx.y * 128 + blockIdx.x] =
        fminf(fminf(red[0], red[1]), fminf(red[2], red[3]));
}

// Kernel 5b: final max(-S) per tensor
__global__ void k_sfinal(float* __restrict__ ws) {
  const float* part = ws + OFF_PART;
  float* maxv = ws + OFF_MAX;
  const int tens = threadIdx.x >> 7;
  const int i = threadIdx.x & 127;
  float m = part[tens * 128 + i];
  #pragma unroll
  for (int off = 32; off; off >>= 1) m = fminf(m, __shfl_xor(m, off));
  __shared__ float red[4];
  const int lane = threadIdx.x & 63, wid = threadIdx.x >> 6;
  if (lane == 0) red[wid] = m;
  __syncthreads();
  if (threadIdx.x == 0)   maxv[0] = -fminf(red[0], red[1]);
  if (threadIdx.x == 128) maxv[1] = -fminf(red[2], red[3]);
}

// ---------------------------------------------------------------------------
// Kernel 6: loss rows; per-wave register accumulation, per-block partial.
__global__ __launch_bounds__(256) void k_loss(float* __restrict__ ws) {
  const int lane = threadIdx.x & 63, wid = threadIdx.x >> 6;
  const int wglobal = blockIdx.x * 4 + wid;   // 0..1023
  const float* Smax = ws + OFF_MAX;
  double acc = 0.0;
  #pragma unroll 4
  for (int r = 0; r < 16; ++r) {
    int gw = wglobal * 16 + r;                // 0..16383
    int tens = gw >> 13;
    int rem = gw & 8191;                      // t*64 + b
    const float* S = ws + (tens ? OFF_S2 : OFF_S1);
    float maxv = Smax[tens];
    float ev = expf(S[(size_t)rem * 64 + lane] + maxv);
    float sum = ev;
    #pragma unroll
    for (int off = 32; off; off >>= 1) sum += __shfl_xor(sum, off);
    float diag = __shfl(ev, rem & 63);
    if (lane == 0) acc += (double)logf(diag / (sum + 1e-5f));
  }
  __shared__ double red[4];
  if (lane == 0) red[wid] = acc;
  __syncthreads();
  if (threadIdx.x == 0)
    ((double*)(ws + OFF_PACC))[blockIdx.x] = red[0] + red[1] + red[2] + red[3];
}

// Kernel 7: reduce 256 per-block partials, finalize loss
__global__ void k_fin(const float* __restrict__ ws, float* __restrict__ out) {
  const double* p = (const double*)(ws + OFF_PACC);
  const int lane = threadIdx.x & 63, wid = threadIdx.x >> 6;
  double v = p[threadIdx.x];
  #pragma unroll
  for (int off = 32; off; off >>= 1) v += __shfl_xor(v, off);
  __shared__ double red[4];
  if (lane == 0) red[wid] = v;
  __syncthreads();
  if (threadIdx.x == 0)
    out[0] = (float)(-(red[0] + red[1] + red[2] + red[3]) / 16384.0);
}

// ---------------------------------------------------------------------------
extern "C" void kernel_launch(void* const* d_in, const int* in_sizes, int n_in,
                              void* d_out, int out_size, void* d_ws, size_t ws_size,
                              hipStream_t stream) {
  const float* A = (const float*)d_in[0];
  const float* V = (const float*)d_in[1];
  const float* E = (const float*)d_in[2];
  float* out = (float*)d_out;
  float* ws  = (float*)d_ws;

  k_sumsq  <<<dim3(4352), dim3(256), 0, stream>>>(A, V, E, ws);
  k_dist   <<<dim3(8, 64, 2), dim3(256), 0, stream>>>(A, V, E, ws);
  k_rowstats<<<dim3(2048, 2), dim3(256), 0, stream>>>(A, V, E, ws, out);
  k_sgemm  <<<dim3(128, 2), dim3(256), 0, stream>>>(ws);
  k_smin   <<<dim3(128, 2), dim3(256), 0, stream>>>(ws);
  k_sfinal <<<dim3(1), dim3(256), 0, stream>>>(ws);
  k_loss   <<<dim3(256), dim3(256), 0, stream>>>(ws);
  k_fin    <<<dim3(1), dim3(256), 0, stream>>>(ws, out);
}

// Round 8
// 231.077 us; speedup vs baseline: 2.9035x; 2.9035x over previous
//
#include <hip/hip_runtime.h>

// Problem sizes
#define NROWS 8192   // B*T
#define MCB   1024   // codebook size M
#define DD    256    // feature dim D
#define TT    128    // T
#define BB    64     // B

// ws offsets (in floats)
#define OFF_DA      0ul
#define OFF_DV      8388608ul
#define OFF_XX_A    16777216ul
#define OFF_XX_V    16785408ul
#define OFF_EE      16793600ul
#define OFF_SMIN_A  16794624ul
#define OFF_LZ1_A   16802816ul
#define OFF_IZ2_A   16811008ul
#define OFF_IDX_A   16819200ul
#define OFF_SMIN_V  16827392ul
#define OFF_LZ1_V   16835584ul
#define OFF_IZ2_V   16843776ul
#define OFF_IDX_V   16851968ul
#define OFF_S1      16860160ul
#define OFF_S2      17384448ul
#define OFF_PART    17908736ul
#define OFF_MAX     17908992ul
#define OFF_PACC    17909000ul   // 256 doubles, per-block loss partials

// ---------------------------------------------------------------------------
__device__ __forceinline__ void gload_lds16(const float* gsrc, float* ldst) {
  __builtin_amdgcn_global_load_lds(
      (const __attribute__((address_space(1))) void*)gsrc,
      (__attribute__((address_space(3))) void*)ldst, 16, 0, 0);
}

// ---------------------------------------------------------------------------
// Kernel 1: row sums of squares (fp64 accumulate for accuracy)
__global__ void k_sumsq(const float* __restrict__ A, const float* __restrict__ V,
                        const float* __restrict__ E, float* __restrict__ ws) {
  const int lane = threadIdx.x & 63;
  const int wid  = threadIdx.x >> 6;
  const int row = blockIdx.x * 4 + wid;   // 0..17407
  const float* src; float* dst; int r;
  if (row < 8192)       { src = A; r = row;         dst = ws + OFF_XX_A; }
  else if (row < 16384) { src = V; r = row - 8192;  dst = ws + OFF_XX_V; }
  else                  { src = E; r = row - 16384; dst = ws + OFF_EE; }
  float4 x = *(const float4*)(src + (size_t)r * DD + lane * 4);
  double acc = (double)x.x * x.x + (double)x.y * x.y +
               (double)x.z * x.z + (double)x.w * x.w;
  #pragma unroll
  for (int off = 32; off; off >>= 1) acc += __shfl_xor(acc, off);
  if (lane == 0) dst[r] = (float)acc;
}

// ---------------------------------------------------------------------------
// Kernel 2: dist GEMM. d[n,m] = (ee[m] + xx[n]) - 2 * (x[n,:] . e[m,:])
// 128x128 C-tile, 8x8/thread (0.5 B/FLOP LDS demand = balanced vs VALU),
// K-chunk 32, SINGLE 32 KB LDS buffer via global_load_lds (round-6-verified
// staging + XOR swizzle), two barriers per chunk:
//   issue chunk t -> barrier (vmcnt drain, buffer ready) -> compute -> barrier
// The per-chunk drain stall overlaps other co-resident blocks' compute
// (3 blocks/CU at 32 KB LDS / ~148 VGPR).
// Swizzle key=(row>>3)&7 both sides:
//   stage: chunk c=i*256+tid; row=c>>3; global k-quad fetched = (c&7)^key;
//          linear LDS dest c*16 B.
//   read:  idx = row*32 + (k4 ^ (((row>>3)&7)<<2)).
__global__ __launch_bounds__(256) void k_dist(const float* __restrict__ A,
    const float* __restrict__ V, const float* __restrict__ E,
    float* __restrict__ ws) {
  const int z = blockIdx.z;
  const float* X  = z ? V : A;
  const float* xx = ws + (z ? OFF_XX_V : OFF_XX_A);
  const float* ee = ws + OFF_EE;
  float* Dst = ws + (z ? OFF_DV : OFF_DA);

  __shared__ __align__(16) float As[128 * 32];
  __shared__ __align__(16) float Bs[128 * 32];

  const int tid = threadIdx.x;
  const int tx = tid & 15;          // col group: cols tx*8..tx*8+7
  const int ty = tid >> 4;          // row group: rows ty*8..ty*8+7

  // chunked XCD swizzle (512 blocks per z, bijective)
  const int bid = blockIdx.y * 8 + blockIdx.x;        // 0..511
  const int sw  = (bid & 7) * 64 + (bid >> 3);
  const int colb = sw & 7, rowb = sw >> 3;
  const int row0 = rowb * 128;
  const int col0 = colb * 128;

  // staging: 4 A-chunks + 4 B-chunks of 16B per thread per K-chunk
  const float* gA[4]; const float* gB[4]; int ldso[4];
  #pragma unroll
  for (int i = 0; i < 4; ++i) {
    int c = i * 256 + tid;                  // 0..1023
    int r = c >> 3;                         // 0..127
    int ks = ((tid & 7) ^ ((r >> 3) & 7)) << 2;   // swizzled k-offset (floats)
    gA[i] = X + (size_t)(row0 + r) * DD + ks;
    gB[i] = E + (size_t)(col0 + r) * DD + ks;
    ldso[i] = c * 4;                        // linear dest (float offset)
  }

  const int xa = (ty & 7) << 2;
  const int xb = (tx & 7) << 2;

  float acc[8][8] = {};

  for (int t = 0; t < 8; ++t) {
    const int kc = t * 32;
    #pragma unroll
    for (int i = 0; i < 4; ++i) {
      gload_lds16(gA[i] + kc, &As[ldso[i]]);
      gload_lds16(gB[i] + kc, &Bs[ldso[i]]);
    }
    __syncthreads();              // vmcnt drained -> buffer ready
    #pragma unroll
    for (int k4 = 0; k4 < 32; k4 += 4) {
      float4 a[8], b[8];
      #pragma unroll
      for (int i = 0; i < 8; ++i)
        a[i] = *(const float4*)(&As[(ty * 8 + i) * 32 + (k4 ^ xa)]);
      #pragma unroll
      for (int j = 0; j < 8; ++j)
        b[j] = *(const float4*)(&Bs[(tx * 8 + j) * 32 + (k4 ^ xb)]);
      #pragma unroll
      for (int i = 0; i < 8; ++i)
        #pragma unroll
        for (int j = 0; j < 8; ++j) {
          acc[i][j] = fmaf(a[i].x, b[j].x, acc[i][j]);
          acc[i][j] = fmaf(a[i].y, b[j].y, acc[i][j]);
          acc[i][j] = fmaf(a[i].z, b[j].z, acc[i][j]);
          acc[i][j] = fmaf(a[i].w, b[j].w, acc[i][j]);
        }
    }
    __syncthreads();              // all waves done reading before overwrite
  }

  float er[8];
  #pragma unroll
  for (int j = 0; j < 8; ++j) er[j] = ee[col0 + tx * 8 + j];
  #pragma unroll
  for (int i = 0; i < 8; ++i) {
    float xri = xx[row0 + ty * 8 + i];
    float o[8];
    #pragma unroll
    for (int j = 0; j < 8; ++j) o[j] = (er[j] + xri) - 2.0f * acc[i][j];
    float* drow = Dst + (size_t)(row0 + ty * 8 + i) * MCB + col0 + tx * 8;
    *(float4*)(drow)     = *(const float4*)(&o[0]);
    *(float4*)(drow + 4) = *(const float4*)(&o[4]);
  }
}

// ---------------------------------------------------------------------------
// Kernel 3: per-row stats (min/argmin, softmax denominators) + quantize write.
__global__ void k_rowstats(const float* __restrict__ A, const float* __restrict__ V,
                           const float* __restrict__ E, float* __restrict__ ws,
                           float* __restrict__ out) {
  const int z = blockIdx.y;
  const float* Dm = ws + (z ? OFF_DV : OFF_DA);
  const float* X  = z ? V : A;
  float* smin_o = ws + (z ? OFF_SMIN_V : OFF_SMIN_A);
  float* lz1_o  = ws + (z ? OFF_LZ1_V  : OFF_LZ1_A);
  float* iz2_o  = ws + (z ? OFF_IZ2_V  : OFF_IZ2_A);
  int*   idx_o  = (int*)(ws + (z ? OFF_IDX_V : OFF_IDX_A));
  float* qout = out + 1 + (size_t)z * ((size_t)NROWS * DD);

  const int lane = threadIdx.x & 63, wid = threadIdx.x >> 6;
  const int n = blockIdx.x * 4 + wid;
  const float* drow = Dm + (size_t)n * MCB;

  float v[16];
  #pragma unroll
  for (int c = 0; c < 4; ++c) {
    float4 t = *(const float4*)(drow + c * 256 + lane * 4);
    v[c*4+0] = t.x; v[c*4+1] = t.y; v[c*4+2] = t.z; v[c*4+3] = t.w;
  }
  float bv = 3.4e38f; int bi = 0;
  #pragma unroll
  for (int c = 0; c < 4; ++c)
    #pragma unroll
    for (int j = 0; j < 4; ++j) {
      float val = v[c*4+j];
      int m = c * 256 + lane * 4 + j;
      if (val < bv) { bv = val; bi = m; }
    }
  #pragma unroll
  for (int off = 32; off; off >>= 1) {
    float ov = __shfl_xor(bv, off);
    int   oi = __shfl_xor(bi, off);
    if (ov < bv || (ov == bv && oi < bi)) { bv = ov; bi = oi; }
  }
  float smin = sqrtf(fmaxf(bv, 0.0f));
  float z1 = 0.f, z2 = 0.f;
  #pragma unroll
  for (int q = 0; q < 16; ++q) {
    float w = sqrtf(fmaxf(v[q], 0.0f)) - smin;
    z1 += expf(-w);
    z2 += expf(-2.0f * w);
  }
  #pragma unroll
  for (int off = 32; off; off >>= 1) {
    z1 += __shfl_xor(z1, off);
    z2 += __shfl_xor(z2, off);
  }
  if (lane == 0) {
    smin_o[n] = smin;
    lz1_o[n]  = logf(z1);
    iz2_o[n]  = 1.0f / z2;
    idx_o[n]  = bi;
  }
  const float* erow = E + (size_t)bi * DD;
  const float* xrow = X + (size_t)n * DD;
  #pragma unroll
  for (int p = 0; p < 4; ++p) {
    int d0 = p * 64 + lane;
    float xv = xrow[d0];
    float ev = erow[d0];
    qout[(size_t)n * DD + d0] = xv + (ev - xv);
  }
}

// ---------------------------------------------------------------------------
// Kernel 4: S[t,b,c] = sum_m adj_p[b*T+t, m] * logq[c*T+t, m]
__global__ __launch_bounds__(256) void k_sgemm(float* __restrict__ ws) {
  const int z = blockIdx.y;
  const int t = blockIdx.x;
  const float* Dp = ws + (z ? OFF_DV : OFF_DA);
  const float* Dq = ws + (z ? OFF_DA : OFF_DV);
  const float* smin_p = ws + (z ? OFF_SMIN_V : OFF_SMIN_A);
  const float* iz2_p  = ws + (z ? OFF_IZ2_V  : OFF_IZ2_A);
  const float* smin_q = ws + (z ? OFF_SMIN_A : OFF_SMIN_V);
  const float* lz1_q  = ws + (z ? OFF_LZ1_A  : OFF_LZ1_V);
  float* S = ws + (z ? OFF_S2 : OFF_S1);

  __shared__ __align__(16) float PA[64][68];
  __shared__ __align__(16) float LQ[64][68];
  __shared__ float sP[64], izP[64], sQ[64], lzQ[64];

  const int tid = threadIdx.x;
  const int tx = tid & 15, ty = tid >> 4;
  const int lm = tid & 63, wq = tid >> 6;

  if (tid < 64) {
    size_t n = (size_t)tid * TT + t;
    sP[tid] = smin_p[n]; izP[tid] = iz2_p[n];
    sQ[tid] = smin_q[n]; lzQ[tid] = lz1_q[n];
  }
  __syncthreads();

  float acc[4][4] = {};
  for (int mc = 0; mc < MCB; mc += 64) {
    #pragma unroll
    for (int i = 0; i < 16; ++i) {
      int b = i * 4 + wq;
      size_t n = (size_t)b * TT + t;
      float dp = Dp[n * MCB + mc + lm];
      float wp = sqrtf(fmaxf(dp, 0.f)) - sP[b];
      PA[lm][b] = expf(-2.f * wp) * izP[b];
      float dq = Dq[n * MCB + mc + lm];
      float wv = sqrtf(fmaxf(dq, 0.f)) - sQ[b];
      LQ[lm][b] = -wv - lzQ[b];
    }
    __syncthreads();
    #pragma unroll
    for (int mm = 0; mm < 64; ++mm) {
      float4 av = *(const float4*)(&PA[mm][ty << 2]);
      float4 bv = *(const float4*)(&LQ[mm][tx << 2]);
      float aa[4] = {av.x, av.y, av.z, av.w};
      float bb[4] = {bv.x, bv.y, bv.z, bv.w};
      #pragma unroll
      for (int i = 0; i < 4; ++i)
        #pragma unroll
        for (int j = 0; j < 4; ++j)
          acc[i][j] = fmaf(aa[i], bb[j], acc[i][j]);
    }
    __syncthreads();
  }
  #pragma unroll
  for (int i = 0; i < 4; ++i) {
    float4 o = {acc[i][0], acc[i][1], acc[i][2], acc[i][3]};
    *(float4*)(S + ((size_t)t * 64 + (ty << 2) + i) * 64 + (tx << 2)) = o;
  }
}

// ---------------------------------------------------------------------------
// Kernel 5a: partial min over S1/S2
__global__ void k_smin(float* __restrict__ ws) {
  const float* S = ws + (blockIdx.y ? OFF_S2 : OFF_S1);
  float* part = ws + OFF_PART;
  size_t base = (size_t)blockIdx.x * 4096;
  float m = 3.4e38f;
  for (int i = threadIdx.x; i < 4096; i += 256) m = fminf(m, S[base + i]);
  #pragma unroll
  for (int off = 32; off; off >>= 1) m = fminf(m, __shfl_xor(m, off));
  __shared__ float red[4];
  const int lane = threadIdx.x & 63, wid = threadIdx.x >> 6;
  if (lane == 0) red[wid] = m;
  __syncthreads();
  if (threadIdx.x == 0)
    part[blockIdx.y * 128 + blockIdx.x] =
        fminf(fminf(red[0], red[1]), fminf(red[2], red[3]));
}

// Kernel 5b: final max(-S) per tensor
__global__ void k_sfinal(float* __restrict__ ws) {
  const float* part = ws + OFF_PART;
  float* maxv = ws + OFF_MAX;
  const int tens = threadIdx.x >> 7;
  const int i = threadIdx.x & 127;
  float m = part[tens * 128 + i];
  #pragma unroll
  for (int off = 32; off; off >>= 1) m = fminf(m, __shfl_xor(m, off));
  __shared__ float red[4];
  const int lane = threadIdx.x & 63, wid = threadIdx.x >> 6;
  if (lane == 0) red[wid] = m;
  __syncthreads();
  if (threadIdx.x == 0)   maxv[0] = -fminf(red[0], red[1]);
  if (threadIdx.x == 128) maxv[1] = -fminf(red[2], red[3]);
}

// ---------------------------------------------------------------------------
// Kernel 6: loss rows; per-wave register accumulation, per-block partial.
__global__ __launch_bounds__(256) void k_loss(float* __restrict__ ws) {
  const int lane = threadIdx.x & 63, wid = threadIdx.x >> 6;
  const int wglobal = blockIdx.x * 4 + wid;   // 0..1023
  const float* Smax = ws + OFF_MAX;
  double acc = 0.0;
  #pragma unroll 4
  for (int r = 0; r < 16; ++r) {
    int gw = wglobal * 16 + r;                // 0..16383
    int tens = gw >> 13;
    int rem = gw & 8191;                      // t*64 + b
    const float* S = ws + (tens ? OFF_S2 : OFF_S1);
    float maxv = Smax[tens];
    float ev = expf(S[(size_t)rem * 64 + lane] + maxv);
    float sum = ev;
    #pragma unroll
    for (int off = 32; off; off >>= 1) sum += __shfl_xor(sum, off);
    float diag = __shfl(ev, rem & 63);
    if (lane == 0) acc += (double)logf(diag / (sum + 1e-5f));
  }
  __shared__ double red[4];
  if (lane == 0) red[wid] = acc;
  __syncthreads();
  if (threadIdx.x == 0)
    ((double*)(ws + OFF_PACC))[blockIdx.x] = red[0] + red[1] + red[2] + red[3];
}

// Kernel 7: reduce 256 per-block partials, finalize loss
__global__ void k_fin(const float* __restrict__ ws, float* __restrict__ out) {
  const double* p = (const double*)(ws + OFF_PACC);
  const int lane = threadIdx.x & 63, wid = threadIdx.x >> 6;
  double v = p[threadIdx.x];
  #pragma unroll
  for (int off = 32; off; off >>= 1) v += __shfl_xor(v, off);
  __shared__ double red[4];
  if (lane == 0) red[wid] = v;
  __syncthreads();
  if (threadIdx.x == 0)
    out[0] = (float)(-(red[0] + red[1] + red[2] + red[3]) / 16384.0);
}

// ---------------------------------------------------------------------------
extern "C" void kernel_launch(void* const* d_in, const int* in_sizes, int n_in,
                              void* d_out, int out_size, void* d_ws, size_t ws_size,
                              hipStream_t stream) {
  const float* A = (const float*)d_in[0];
  const float* V = (const float*)d_in[1];
  const float* E = (const float*)d_in[2];
  float* out = (float*)d_out;
  float* ws  = (float*)d_ws;

  k_sumsq  <<<dim3(4352), dim3(256), 0, stream>>>(A, V, E, ws);
  k_dist   <<<dim3(8, 64, 2), dim3(256), 0, stream>>>(A, V, E, ws);
  k_rowstats<<<dim3(2048, 2), dim3(256), 0, stream>>>(A, V, E, ws, out);
  k_sgemm  <<<dim3(128, 2), dim3(256), 0, stream>>>(ws);
  k_smin   <<<dim3(128, 2), dim3(256), 0, stream>>>(ws);
  k_sfinal <<<dim3(1), dim3(256), 0, stream>>>(ws);
  k_loss   <<<dim3(256), dim3(256), 0, stream>>>(ws);
  k_fin    <<<dim3(1), dim3(256), 0, stream>>>(ws, out);
}

// Round 9
// 228.794 us; speedup vs baseline: 2.9325x; 1.0100x over previous
//
#include <hip/hip_runtime.h>

// Problem sizes
#define NROWS 8192   // B*T
#define MCB   1024   // codebook size M
#define DD    256    // feature dim D
#define TT    128    // T
#define BB    64     // B

// ws offsets (in floats)
#define OFF_DA      0ul
#define OFF_DV      8388608ul
#define OFF_XX_A    16777216ul
#define OFF_XX_V    16785408ul
#define OFF_EE      16793600ul
#define OFF_SMIN_A  16794624ul
#define OFF_LZ1_A   16802816ul
#define OFF_IZ2_A   16811008ul
#define OFF_IDX_A   16819200ul
#define OFF_SMIN_V  16827392ul
#define OFF_LZ1_V   16835584ul
#define OFF_IZ2_V   16843776ul
#define OFF_IDX_V   16851968ul
#define OFF_S1      16860160ul
#define OFF_S2      17384448ul
#define OFF_PART    17908736ul
#define OFF_MAX     17908992ul
#define OFF_PACC    17909000ul   // 256 doubles, per-block loss partials

// ---------------------------------------------------------------------------
__device__ __forceinline__ void gload_lds16(const float* gsrc, float* ldst) {
  __builtin_amdgcn_global_load_lds(
      (const __attribute__((address_space(1))) void*)gsrc,
      (__attribute__((address_space(3))) void*)ldst, 16, 0, 0);
}

// ---------------------------------------------------------------------------
// Kernel 1: row sums of squares (fp64 accumulate for accuracy)
__global__ void k_sumsq(const float* __restrict__ A, const float* __restrict__ V,
                        const float* __restrict__ E, float* __restrict__ ws) {
  const int lane = threadIdx.x & 63;
  const int wid  = threadIdx.x >> 6;
  const int row = blockIdx.x * 4 + wid;   // 0..17407
  const float* src; float* dst; int r;
  if (row < 8192)       { src = A; r = row;         dst = ws + OFF_XX_A; }
  else if (row < 16384) { src = V; r = row - 8192;  dst = ws + OFF_XX_V; }
  else                  { src = E; r = row - 16384; dst = ws + OFF_EE; }
  float4 x = *(const float4*)(src + (size_t)r * DD + lane * 4);
  double acc = (double)x.x * x.x + (double)x.y * x.y +
               (double)x.z * x.z + (double)x.w * x.w;
  #pragma unroll
  for (int off = 32; off; off >>= 1) acc += __shfl_xor(acc, off);
  if (lane == 0) dst[r] = (float)acc;
}

// ---------------------------------------------------------------------------
// Kernel 2: dist GEMM. d[n,m] = (ee[m] + xx[n]) - 2 * (x[n,:] . e[m,:])
// 128x128 C-tile, 8x8/thread, K-chunk 32, single 32 KB LDS buffer via
// global_load_lds, verified XOR swizzle key=(row>>3)&7 both sides.
// (Round-8 structure, unchanged except setprio around the FMA block.)
__global__ __launch_bounds__(256) void k_dist(const float* __restrict__ A,
    const float* __restrict__ V, const float* __restrict__ E,
    float* __restrict__ ws) {
  const int z = blockIdx.z;
  const float* X  = z ? V : A;
  const float* xx = ws + (z ? OFF_XX_V : OFF_XX_A);
  const float* ee = ws + OFF_EE;
  float* Dst = ws + (z ? OFF_DV : OFF_DA);

  __shared__ __align__(16) float As[128 * 32];
  __shared__ __align__(16) float Bs[128 * 32];

  const int tid = threadIdx.x;
  const int tx = tid & 15;          // col group: cols tx*8..tx*8+7
  const int ty = tid >> 4;          // row group: rows ty*8..ty*8+7

  // chunked XCD swizzle (512 blocks per z, bijective)
  const int bid = blockIdx.y * 8 + blockIdx.x;        // 0..511
  const int sw  = (bid & 7) * 64 + (bid >> 3);
  const int colb = sw & 7, rowb = sw >> 3;
  const int row0 = rowb * 128;
  const int col0 = colb * 128;

  // staging: 4 A-chunks + 4 B-chunks of 16B per thread per K-chunk
  const float* gA[4]; const float* gB[4]; int ldso[4];
  #pragma unroll
  for (int i = 0; i < 4; ++i) {
    int c = i * 256 + tid;                  // 0..1023
    int r = c >> 3;                         // 0..127
    int ks = ((tid & 7) ^ ((r >> 3) & 7)) << 2;   // swizzled k-offset (floats)
    gA[i] = X + (size_t)(row0 + r) * DD + ks;
    gB[i] = E + (size_t)(col0 + r) * DD + ks;
    ldso[i] = c * 4;                        // linear dest (float offset)
  }

  const int xa = (ty & 7) << 2;
  const int xb = (tx & 7) << 2;

  float acc[8][8] = {};

  for (int t = 0; t < 8; ++t) {
    const int kc = t * 32;
    #pragma unroll
    for (int i = 0; i < 4; ++i) {
      gload_lds16(gA[i] + kc, &As[ldso[i]]);
      gload_lds16(gB[i] + kc, &Bs[ldso[i]]);
    }
    __syncthreads();              // vmcnt drained -> buffer ready
    __builtin_amdgcn_s_setprio(1);
    #pragma unroll
    for (int k4 = 0; k4 < 32; k4 += 4) {
      float4 a[8], b[8];
      #pragma unroll
      for (int i = 0; i < 8; ++i)
        a[i] = *(const float4*)(&As[(ty * 8 + i) * 32 + (k4 ^ xa)]);
      #pragma unroll
      for (int j = 0; j < 8; ++j)
        b[j] = *(const float4*)(&Bs[(tx * 8 + j) * 32 + (k4 ^ xb)]);
      #pragma unroll
      for (int i = 0; i < 8; ++i)
        #pragma unroll
        for (int j = 0; j < 8; ++j) {
          acc[i][j] = fmaf(a[i].x, b[j].x, acc[i][j]);
          acc[i][j] = fmaf(a[i].y, b[j].y, acc[i][j]);
          acc[i][j] = fmaf(a[i].z, b[j].z, acc[i][j]);
          acc[i][j] = fmaf(a[i].w, b[j].w, acc[i][j]);
        }
    }
    __builtin_amdgcn_s_setprio(0);
    __syncthreads();              // all waves done reading before overwrite
  }

  float er[8];
  #pragma unroll
  for (int j = 0; j < 8; ++j) er[j] = ee[col0 + tx * 8 + j];
  #pragma unroll
  for (int i = 0; i < 8; ++i) {
    float xri = xx[row0 + ty * 8 + i];
    float o[8];
    #pragma unroll
    for (int j = 0; j < 8; ++j) o[j] = (er[j] + xri) - 2.0f * acc[i][j];
    float* drow = Dst + (size_t)(row0 + ty * 8 + i) * MCB + col0 + tx * 8;
    *(float4*)(drow)     = *(const float4*)(&o[0]);
    *(float4*)(drow + 4) = *(const float4*)(&o[4]);
  }
}

// ---------------------------------------------------------------------------
// Kernel 3: per-row stats (min/argmin, softmax denominators) + quantize write.
// argmin path untouched (exact fp32); z1/z2/lz1 are loss-path-only -> fast exp.
__global__ void k_rowstats(const float* __restrict__ A, const float* __restrict__ V,
                           const float* __restrict__ E, float* __restrict__ ws,
                           float* __restrict__ out) {
  const int z = blockIdx.y;
  const float* Dm = ws + (z ? OFF_DV : OFF_DA);
  const float* X  = z ? V : A;
  float* smin_o = ws + (z ? OFF_SMIN_V : OFF_SMIN_A);
  float* lz1_o  = ws + (z ? OFF_LZ1_V  : OFF_LZ1_A);
  float* iz2_o  = ws + (z ? OFF_IZ2_V  : OFF_IZ2_A);
  int*   idx_o  = (int*)(ws + (z ? OFF_IDX_V : OFF_IDX_A));
  float* qout = out + 1 + (size_t)z * ((size_t)NROWS * DD);

  const int lane = threadIdx.x & 63, wid = threadIdx.x >> 6;
  const int n = blockIdx.x * 4 + wid;
  const float* drow = Dm + (size_t)n * MCB;

  float v[16];
  #pragma unroll
  for (int c = 0; c < 4; ++c) {
    float4 t = *(const float4*)(drow + c * 256 + lane * 4);
    v[c*4+0] = t.x; v[c*4+1] = t.y; v[c*4+2] = t.z; v[c*4+3] = t.w;
  }
  float bv = 3.4e38f; int bi = 0;
  #pragma unroll
  for (int c = 0; c < 4; ++c)
    #pragma unroll
    for (int j = 0; j < 4; ++j) {
      float val = v[c*4+j];
      int m = c * 256 + lane * 4 + j;
      if (val < bv) { bv = val; bi = m; }
    }
  #pragma unroll
  for (int off = 32; off; off >>= 1) {
    float ov = __shfl_xor(bv, off);
    int   oi = __shfl_xor(bi, off);
    if (ov < bv || (ov == bv && oi < bi)) { bv = ov; bi = oi; }
  }
  float smin = sqrtf(fmaxf(bv, 0.0f));
  float z1 = 0.f, z2 = 0.f;
  #pragma unroll
  for (int q = 0; q < 16; ++q) {
    float w = sqrtf(fmaxf(v[q], 0.0f)) - smin;
    z1 += __expf(-w);
    z2 += __expf(-2.0f * w);
  }
  #pragma unroll
  for (int off = 32; off; off >>= 1) {
    z1 += __shfl_xor(z1, off);
    z2 += __shfl_xor(z2, off);
  }
  if (lane == 0) {
    smin_o[n] = smin;
    lz1_o[n]  = __logf(z1);
    iz2_o[n]  = 1.0f / z2;
    idx_o[n]  = bi;
  }
  const float* erow = E + (size_t)bi * DD;
  const float* xrow = X + (size_t)n * DD;
  #pragma unroll
  for (int p = 0; p < 4; ++p) {
    int d0 = p * 64 + lane;
    float xv = xrow[d0];
    float ev = erow[d0];
    qout[(size_t)n * DD + d0] = xv + (ev - xv);
  }
}

// ---------------------------------------------------------------------------
// Kernel 4: S[t,b,c] = -izP[b] * (sum_m exp(-2wp[b,m]) * wv[c,m]) - lzQ[c]
// (algebraic hoist: Sum_m adj_p = 1 exactly, so lzQ/izP move to the epilogue)
// Double-buffered staging (one barrier per chunk; transform of chunk t+1
// overlaps GEMM of chunk t), fast __expf (loss path only).
// Fused epilogue: per-block min(S) -> part[z*128+t]  (k_smin eliminated).
__global__ __launch_bounds__(256) void k_sgemm(float* __restrict__ ws) {
  const int z = blockIdx.y;
  const int t = blockIdx.x;
  const float* Dp = ws + (z ? OFF_DV : OFF_DA);
  const float* Dq = ws + (z ? OFF_DA : OFF_DV);
  const float* smin_p = ws + (z ? OFF_SMIN_V : OFF_SMIN_A);
  const float* iz2_p  = ws + (z ? OFF_IZ2_V  : OFF_IZ2_A);
  const float* smin_q = ws + (z ? OFF_SMIN_A : OFF_SMIN_V);
  const float* lz1_q  = ws + (z ? OFF_LZ1_A  : OFF_LZ1_V);
  float* S = ws + (z ? OFF_S2 : OFF_S1);
  float* part = ws + OFF_PART;

  __shared__ __align__(16) float PA[2][64][68];
  __shared__ __align__(16) float WQ[2][64][68];
  __shared__ float sP[64], izP[64], sQ[64], lzQ[64];
  __shared__ float redmin[4];

  const int tid = threadIdx.x;
  const int tx = tid & 15, ty = tid >> 4;
  const int lm = tid & 63, wq = tid >> 6;

  if (tid < 64) {
    size_t n = (size_t)tid * TT + t;
    sP[tid] = smin_p[n]; izP[tid] = iz2_p[n];
    sQ[tid] = smin_q[n]; lzQ[tid] = lz1_q[n];
  }
  __syncthreads();

  // stage chunk 0 -> buf 0
  #pragma unroll
  for (int i = 0; i < 16; ++i) {
    int b = i * 4 + wq;
    size_t n = (size_t)b * TT + t;
    float dp = Dp[n * MCB + lm];
    PA[0][lm][b] = __expf(-2.f * (sqrtf(fmaxf(dp, 0.f)) - sP[b]));
    float dq = Dq[n * MCB + lm];
    WQ[0][lm][b] = sqrtf(fmaxf(dq, 0.f)) - sQ[b];
  }
  __syncthreads();

  float acc[4][4] = {};
  for (int ch = 0; ch < 16; ++ch) {
    const int cur = ch & 1;
    if (ch < 15) {
      const int mc = (ch + 1) * 64;
      #pragma unroll
      for (int i = 0; i < 16; ++i) {
        int b = i * 4 + wq;
        size_t n = (size_t)b * TT + t;
        float dp = Dp[n * MCB + mc + lm];
        PA[cur ^ 1][lm][b] = __expf(-2.f * (sqrtf(fmaxf(dp, 0.f)) - sP[b]));
        float dq = Dq[n * MCB + mc + lm];
        WQ[cur ^ 1][lm][b] = sqrtf(fmaxf(dq, 0.f)) - sQ[b];
      }
    }
    #pragma unroll
    for (int mm = 0; mm < 64; ++mm) {
      float4 av = *(const float4*)(&PA[cur][mm][ty << 2]);
      float4 bv = *(const float4*)(&WQ[cur][mm][tx << 2]);
      float aa[4] = {av.x, av.y, av.z, av.w};
      float bb[4] = {bv.x, bv.y, bv.z, bv.w};
      #pragma unroll
      for (int i = 0; i < 4; ++i)
        #pragma unroll
        for (int j = 0; j < 4; ++j)
          acc[i][j] = fmaf(aa[i], bb[j], acc[i][j]);
    }
    __syncthreads();   // buf[cur] fully read + buf[cur^1] fully staged
  }

  // epilogue: S = -izP[b]*G - lzQ[c]; fused block-min
  float mn = 3.4e38f;
  #pragma unroll
  for (int i = 0; i < 4; ++i) {
    float izb = izP[(ty << 2) + i];
    float o[4];
    #pragma unroll
    for (int j = 0; j < 4; ++j) {
      o[j] = -izb * acc[i][j] - lzQ[(tx << 2) + j];
      mn = fminf(mn, o[j]);
    }
    *(float4*)(S + ((size_t)t * 64 + (ty << 2) + i) * 64 + (tx << 2)) =
        *(const float4*)(&o[0]);
  }
  #pragma unroll
  for (int off = 32; off; off >>= 1) mn = fminf(mn, __shfl_xor(mn, off));
  const int lane = tid & 63;
  if (lane == 0) redmin[wq] = mn;
  __syncthreads();
  if (tid == 0)
    part[z * 128 + t] =
        fminf(fminf(redmin[0], redmin[1]), fminf(redmin[2], redmin[3]));
}

// ---------------------------------------------------------------------------
// Kernel 5: final max(-S) per tensor (reduces the 256 per-block partial mins)
__global__ void k_sfinal(float* __restrict__ ws) {
  const float* part = ws + OFF_PART;
  float* maxv = ws + OFF_MAX;
  const int tens = threadIdx.x >> 7;
  const int i = threadIdx.x & 127;
  float m = part[tens * 128 + i];
  #pragma unroll
  for (int off = 32; off; off >>= 1) m = fminf(m, __shfl_xor(m, off));
  __shared__ float red[4];
  const int lane = threadIdx.x & 63, wid = threadIdx.x >> 6;
  if (lane == 0) red[wid] = m;
  __syncthreads();
  if (threadIdx.x == 0)   maxv[0] = -fminf(red[0], red[1]);
  if (threadIdx.x == 128) maxv[1] = -fminf(red[2], red[3]);
}

// ---------------------------------------------------------------------------
// Kernel 6: loss rows; per-wave register accumulation, per-block partial.
__global__ __launch_bounds__(256) void k_loss(float* __restrict__ ws) {
  const int lane = threadIdx.x & 63, wid = threadIdx.x >> 6;
  const int wglobal = blockIdx.x * 4 + wid;   // 0..1023
  const float* Smax = ws + OFF_MAX;
  double acc = 0.0;
  #pragma unroll 4
  for (int r = 0; r < 16; ++r) {
    int gw = wglobal * 16 + r;                // 0..16383
    int tens = gw >> 13;
    int rem = gw & 8191;                      // t*64 + b
    const float* S = ws + (tens ? OFF_S2 : OFF_S1);
    float maxv = Smax[tens];
    float ev = __expf(S[(size_t)rem * 64 + lane] + maxv);
    float sum = ev;
    #pragma unroll
    for (int off = 32; off; off >>= 1) sum += __shfl_xor(sum, off);
    float diag = __shfl(ev, rem & 63);
    if (lane == 0) acc += (double)__logf(diag / (sum + 1e-5f));
  }
  __shared__ double red[4];
  if (lane == 0) red[wid] = acc;
  __syncthreads();
  if (threadIdx.x == 0)
    ((double*)(ws + OFF_PACC))[blockIdx.x] = red[0] + red[1] + red[2] + red[3];
}

// Kernel 7: reduce 256 per-block partials, finalize loss
__global__ void k_fin(const float* __restrict__ ws, float* __restrict__ out) {
  const double* p = (const double*)(ws + OFF_PACC);
  const int lane = threadIdx.x & 63, wid = threadIdx.x >> 6;
  double v = p[threadIdx.x];
  #pragma unroll
  for (int off = 32; off; off >>= 1) v += __shfl_xor(v, off);
  __shared__ double red[4];
  if (lane == 0) red[wid] = v;
  __syncthreads();
  if (threadIdx.x == 0)
    out[0] = (float)(-(red[0] + red[1] + red[2] + red[3]) / 16384.0);
}

// ---------------------------------------------------------------------------
extern "C" void kernel_launch(void* const* d_in, const int* in_sizes, int n_in,
                              void* d_out, int out_size, void* d_ws, size_t ws_size,
                              hipStream_t stream) {
  const float* A = (const float*)d_in[0];
  const float* V = (const float*)d_in[1];
  const float* E = (const float*)d_in[2];
  float* out = (float*)d_out;
  float* ws  = (float*)d_ws;

  k_sumsq  <<<dim3(4352), dim3(256), 0, stream>>>(A, V, E, ws);
  k_dist   <<<dim3(8, 64, 2), dim3(256), 0, stream>>>(A, V, E, ws);
  k_rowstats<<<dim3(2048, 2), dim3(256), 0, stream>>>(A, V, E, ws, out);
  k_sgemm  <<<dim3(128, 2), dim3(256), 0, stream>>>(ws);
  k_sfinal <<<dim3(1), dim3(256), 0, stream>>>(ws);
  k_loss   <<<dim3(256), dim3(256), 0, stream>>>(ws);
  k_fin    <<<dim3(1), dim3(256), 0, stream>>>(ws, out);
}

// Round 10
// 152.972 us; speedup vs baseline: 4.3860x; 1.4957x over previous
//
#include <hip/hip_runtime.h>

// Problem sizes
#define NROWS 8192   // B*T
#define MCB   1024   // codebook size M
#define DD    256    // feature dim D
#define TT    128    // T
#define BB    64     // B

// ws offsets (in floats)
#define OFF_DA      0ul
#define OFF_DV      8388608ul
#define OFF_XX_A    16777216ul
#define OFF_XX_V    16785408ul
#define OFF_EE      16793600ul
#define OFF_SMIN_A  16794624ul
#define OFF_LZ1_A   16802816ul
#define OFF_IZ2_A   16811008ul
#define OFF_IDX_A   16819200ul
#define OFF_SMIN_V  16827392ul
#define OFF_LZ1_V   16835584ul
#define OFF_IZ2_V   16843776ul
#define OFF_IDX_V   16851968ul
#define OFF_S1      16860160ul
#define OFF_S2      17384448ul
#define OFF_PART    17908736ul
#define OFF_MAX     17908992ul
#define OFF_PACC    17909000ul   // 256 doubles, per-block loss partials
// split-bf16 planes (ushort arrays), 16B-aligned float offsets:
#define OFF_HIA     17909504ul   // 8192*256 ushorts = 1048576 floats
#define OFF_LOA     (OFF_HIA + 1048576ul)
#define OFF_HIV     (OFF_HIA + 2097152ul)
#define OFF_LOV     (OFF_HIA + 3145728ul)
#define OFF_HIE     (OFF_HIA + 4194304ul)   // 1024*256 ushorts = 131072 floats
#define OFF_LOE     (OFF_HIE + 131072ul)
// total ~22,366,000 floats ~ 89.5 MB of ws

typedef __attribute__((ext_vector_type(8))) short bf16x8;
typedef __attribute__((ext_vector_type(4))) float f32x4;

// ---------------------------------------------------------------------------
__device__ __forceinline__ void gload_lds16u(const ushort* gsrc, ushort* ldst) {
  __builtin_amdgcn_global_load_lds(
      (const __attribute__((address_space(1))) void*)gsrc,
      (__attribute__((address_space(3))) void*)ldst, 16, 0, 0);
}
__device__ __forceinline__ ushort bf16_rne(float x) {
  unsigned u = __float_as_uint(x);
  unsigned r = u + 0x7FFFu + ((u >> 16) & 1u);
  return (ushort)(r >> 16);
}
__device__ __forceinline__ float bf16_f(ushort h) {
  return __uint_as_float((unsigned)h << 16);
}

// ---------------------------------------------------------------------------
// Kernel 1: row sums of squares (fp64 accumulate) + split-bf16 hi/lo planes.
__global__ void k_sumsq(const float* __restrict__ A, const float* __restrict__ V,
                        const float* __restrict__ E, float* __restrict__ ws) {
  const int lane = threadIdx.x & 63;
  const int wid  = threadIdx.x >> 6;
  const int row = blockIdx.x * 4 + wid;   // 0..17407
  const float* src; float* dst; ushort* hi; ushort* lo; int r;
  if (row < 8192)       { src = A; r = row;         dst = ws + OFF_XX_A;
                          hi = (ushort*)(ws + OFF_HIA); lo = (ushort*)(ws + OFF_LOA); }
  else if (row < 16384) { src = V; r = row - 8192;  dst = ws + OFF_XX_V;
                          hi = (ushort*)(ws + OFF_HIV); lo = (ushort*)(ws + OFF_LOV); }
  else                  { src = E; r = row - 16384; dst = ws + OFF_EE;
                          hi = (ushort*)(ws + OFF_HIE); lo = (ushort*)(ws + OFF_LOE); }
  float4 x = *(const float4*)(src + (size_t)r * DD + lane * 4);
  // split
  ushort4 h, l;
  h.x = bf16_rne(x.x); l.x = bf16_rne(x.x - bf16_f(h.x));
  h.y = bf16_rne(x.y); l.y = bf16_rne(x.y - bf16_f(h.y));
  h.z = bf16_rne(x.z); l.z = bf16_rne(x.z - bf16_f(h.z));
  h.w = bf16_rne(x.w); l.w = bf16_rne(x.w - bf16_f(h.w));
  *(ushort4*)(hi + (size_t)r * DD + lane * 4) = h;
  *(ushort4*)(lo + (size_t)r * DD + lane * 4) = l;
  // sum of squares (exact path, unchanged)
  double acc = (double)x.x * x.x + (double)x.y * x.y +
               (double)x.z * x.z + (double)x.w * x.w;
  #pragma unroll
  for (int off = 32; off; off >>= 1) acc += __shfl_xor(acc, off);
  if (lane == 0) dst[r] = (float)acc;
}

// ---------------------------------------------------------------------------
// Kernel 2: dist GEMM via split-bf16 MFMA (hi*hi + hi*lo + lo*hi).
// d[n,m] = (ee[m] + xx[n]) - 2 * G[n,m]
// 128x128 tile, 4 waves (2x2), each wave 64x64 = 4x4 frags of 16x16x32.
// Single 32 KB LDS (4 planes [128][32] bf16) via global_load_lds, 2 barriers
// per K-chunk (round-8-proven). 16B-granule XOR swizzle pg = kg^((r>>1)&3)
// on stage-source and frag-read (per-16-lane: every bank-quad x2 = free).
// C/D layout (m89-verified): col = lane&15, row = (lane>>4)*4 + reg.
__global__ __launch_bounds__(256) void k_dist(const float* __restrict__ A,
    const float* __restrict__ V, const float* __restrict__ E,
    float* __restrict__ ws) {
  const int z = blockIdx.z;
  const ushort* Xhi = (const ushort*)(ws + (z ? OFF_HIV : OFF_HIA));
  const ushort* Xlo = (const ushort*)(ws + (z ? OFF_LOV : OFF_LOA));
  const ushort* Ehi = (const ushort*)(ws + OFF_HIE);
  const ushort* Elo = (const ushort*)(ws + OFF_LOE);
  const float* xx = ws + (z ? OFF_XX_V : OFF_XX_A);
  const float* ee = ws + OFF_EE;
  float* Dst = ws + (z ? OFF_DV : OFF_DA);

  __shared__ __align__(16) ushort LAhi[128 * 32];
  __shared__ __align__(16) ushort LAlo[128 * 32];
  __shared__ __align__(16) ushort LBhi[128 * 32];
  __shared__ __align__(16) ushort LBlo[128 * 32];

  const int tid = threadIdx.x;
  // chunked XCD swizzle (512 blocks per z, bijective)
  const int bid = blockIdx.y * 8 + blockIdx.x;        // 0..511
  const int sw  = (bid & 7) * 64 + (bid >> 3);
  const int colb = sw & 7, rowb = sw >> 3;
  const int row0 = rowb * 128;
  const int col0 = colb * 128;

  const int wv = tid >> 6, lane = tid & 63;
  const int wr = wv >> 1, wc = wv & 1;                // wave tile (64x64)
  const int rl = lane & 15, kg = lane >> 4;

  // staging: 2 granules (16B) per thread per plane; granule c: r=c>>2, pg=c&3
  const int c0 = tid, c1 = 256 + tid;
  const int r0 = c0 >> 2, lg0 = (c0 & 3) ^ ((r0 >> 1) & 3);
  const int r1 = c1 >> 2, lg1 = (c1 & 3) ^ ((r1 >> 1) & 3);
  const ushort* gAhi0 = Xhi + (size_t)(row0 + r0) * DD + lg0 * 8;
  const ushort* gAhi1 = Xhi + (size_t)(row0 + r1) * DD + lg1 * 8;
  const ushort* gAlo0 = Xlo + (size_t)(row0 + r0) * DD + lg0 * 8;
  const ushort* gAlo1 = Xlo + (size_t)(row0 + r1) * DD + lg1 * 8;
  const ushort* gBhi0 = Ehi + (size_t)(col0 + r0) * DD + lg0 * 8;
  const ushort* gBhi1 = Ehi + (size_t)(col0 + r1) * DD + lg1 * 8;
  const ushort* gBlo0 = Elo + (size_t)(col0 + r0) * DD + lg0 * 8;
  const ushort* gBlo1 = Elo + (size_t)(col0 + r1) * DD + lg1 * 8;
  const int d0 = c0 * 8, d1 = c1 * 8;   // linear LDS dest (ushort offset)

  // frag read addresses (constant across chunks; single buffer)
  int aidx[4], bidx[4];
  #pragma unroll
  for (int f = 0; f < 4; ++f) {
    int ra = wr * 64 + f * 16 + rl;
    aidx[f] = ra * 32 + ((kg ^ ((ra >> 1) & 3)) << 3);
    int rb = wc * 64 + f * 16 + rl;
    bidx[f] = rb * 32 + ((kg ^ ((rb >> 1) & 3)) << 3);
  }

  f32x4 acc[4][4] = {};

  for (int t = 0; t < 8; ++t) {
    const int kc = t * 32;
    gload_lds16u(gAhi0 + kc, &LAhi[d0]);
    gload_lds16u(gAhi1 + kc, &LAhi[d1]);
    gload_lds16u(gAlo0 + kc, &LAlo[d0]);
    gload_lds16u(gAlo1 + kc, &LAlo[d1]);
    gload_lds16u(gBhi0 + kc, &LBhi[d0]);
    gload_lds16u(gBhi1 + kc, &LBhi[d1]);
    gload_lds16u(gBlo0 + kc, &LBlo[d0]);
    gload_lds16u(gBlo1 + kc, &LBlo[d1]);
    __syncthreads();              // vmcnt drained -> planes ready
    __builtin_amdgcn_s_setprio(1);
    bf16x8 ahi[4], alo[4], bhi[4], blo[4];
    #pragma unroll
    for (int f = 0; f < 4; ++f) {
      ahi[f] = *(const bf16x8*)(&LAhi[aidx[f]]);
      alo[f] = *(const bf16x8*)(&LAlo[aidx[f]]);
      bhi[f] = *(const bf16x8*)(&LBhi[bidx[f]]);
      blo[f] = *(const bf16x8*)(&LBlo[bidx[f]]);
    }
    #pragma unroll
    for (int fr = 0; fr < 4; ++fr)
      #pragma unroll
      for (int fc = 0; fc < 4; ++fc) {
        acc[fr][fc] = __builtin_amdgcn_mfma_f32_16x16x32_bf16(
            ahi[fr], bhi[fc], acc[fr][fc], 0, 0, 0);
        acc[fr][fc] = __builtin_amdgcn_mfma_f32_16x16x32_bf16(
            ahi[fr], blo[fc], acc[fr][fc], 0, 0, 0);
        acc[fr][fc] = __builtin_amdgcn_mfma_f32_16x16x32_bf16(
            alo[fr], bhi[fc], acc[fr][fc], 0, 0, 0);
      }
    __builtin_amdgcn_s_setprio(0);
    __syncthreads();              // all waves done reading before overwrite
  }

  // epilogue: exact formula, C layout col=lane&15 row=(lane>>4)*4+v
  float xn[4][4];
  #pragma unroll
  for (int fr = 0; fr < 4; ++fr)
    #pragma unroll
    for (int v = 0; v < 4; ++v)
      xn[fr][v] = xx[row0 + wr * 64 + fr * 16 + kg * 4 + v];
  #pragma unroll
  for (int fc = 0; fc < 4; ++fc) {
    const int m = col0 + wc * 64 + fc * 16 + rl;
    const float em = ee[m];
    #pragma unroll
    for (int fr = 0; fr < 4; ++fr) {
      #pragma unroll
      for (int v = 0; v < 4; ++v) {
        const int n = row0 + wr * 64 + fr * 16 + kg * 4 + v;
        Dst[(size_t)n * MCB + m] = (em + xn[fr][v]) - 2.0f * acc[fr][fc][v];
      }
    }
  }
}

// ---------------------------------------------------------------------------
// Kernel 3: per-row stats (min/argmin, softmax denominators) + quantize write.
__global__ void k_rowstats(const float* __restrict__ A, const float* __restrict__ V,
                           const float* __restrict__ E, float* __restrict__ ws,
                           float* __restrict__ out) {
  const int z = blockIdx.y;
  const float* Dm = ws + (z ? OFF_DV : OFF_DA);
  const float* X  = z ? V : A;
  float* smin_o = ws + (z ? OFF_SMIN_V : OFF_SMIN_A);
  float* lz1_o  = ws + (z ? OFF_LZ1_V  : OFF_LZ1_A);
  float* iz2_o  = ws + (z ? OFF_IZ2_V  : OFF_IZ2_A);
  int*   idx_o  = (int*)(ws + (z ? OFF_IDX_V : OFF_IDX_A));
  float* qout = out + 1 + (size_t)z * ((size_t)NROWS * DD);

  const int lane = threadIdx.x & 63, wid = threadIdx.x >> 6;
  const int n = blockIdx.x * 4 + wid;
  const float* drow = Dm + (size_t)n * MCB;

  float v[16];
  #pragma unroll
  for (int c = 0; c < 4; ++c) {
    float4 t = *(const float4*)(drow + c * 256 + lane * 4);
    v[c*4+0] = t.x; v[c*4+1] = t.y; v[c*4+2] = t.z; v[c*4+3] = t.w;
  }
  float bv = 3.4e38f; int bi = 0;
  #pragma unroll
  for (int c = 0; c < 4; ++c)
    #pragma unroll
    for (int j = 0; j < 4; ++j) {
      float val = v[c*4+j];
      int m = c * 256 + lane * 4 + j;
      if (val < bv) { bv = val; bi = m; }
    }
  #pragma unroll
  for (int off = 32; off; off >>= 1) {
    float ov = __shfl_xor(bv, off);
    int   oi = __shfl_xor(bi, off);
    if (ov < bv || (ov == bv && oi < bi)) { bv = ov; bi = oi; }
  }
  float smin = sqrtf(fmaxf(bv, 0.0f));
  float z1 = 0.f, z2 = 0.f;
  #pragma unroll
  for (int q = 0; q < 16; ++q) {
    float w = sqrtf(fmaxf(v[q], 0.0f)) - smin;
    z1 += __expf(-w);
    z2 += __expf(-2.0f * w);
  }
  #pragma unroll
  for (int off = 32; off; off >>= 1) {
    z1 += __shfl_xor(z1, off);
    z2 += __shfl_xor(z2, off);
  }
  if (lane == 0) {
    smin_o[n] = smin;
    lz1_o[n]  = __logf(z1);
    iz2_o[n]  = 1.0f / z2;
    idx_o[n]  = bi;
  }
  const float* erow = E + (size_t)bi * DD;
  const float* xrow = X + (size_t)n * DD;
  #pragma unroll
  for (int p = 0; p < 4; ++p) {
    int dd = p * 64 + lane;
    float xv = xrow[dd];
    float ev = erow[dd];
    qout[(size_t)n * DD + dd] = xv + (ev - xv);
  }
}

// ---------------------------------------------------------------------------
// Kernel 4: S[t,b,c] = -izP[b]*(sum_m exp(-2wp)*wv) - lzQ[c]; dbuf staging,
// fast __expf (loss path only), fused per-block min -> part[].
__global__ __launch_bounds__(256) void k_sgemm(float* __restrict__ ws) {
  const int z = blockIdx.y;
  const int t = blockIdx.x;
  const float* Dp = ws + (z ? OFF_DV : OFF_DA);
  const float* Dq = ws + (z ? OFF_DA : OFF_DV);
  const float* smin_p = ws + (z ? OFF_SMIN_V : OFF_SMIN_A);
  const float* iz2_p  = ws + (z ? OFF_IZ2_V  : OFF_IZ2_A);
  const float* smin_q = ws + (z ? OFF_SMIN_A : OFF_SMIN_V);
  const float* lz1_q  = ws + (z ? OFF_LZ1_A  : OFF_LZ1_V);
  float* S = ws + (z ? OFF_S2 : OFF_S1);
  float* part = ws + OFF_PART;

  __shared__ __align__(16) float PA[2][64][68];
  __shared__ __align__(16) float WQ[2][64][68];
  __shared__ float sP[64], izP[64], sQ[64], lzQ[64];
  __shared__ float redmin[4];

  const int tid = threadIdx.x;
  const int tx = tid & 15, ty = tid >> 4;
  const int lm = tid & 63, wq = tid >> 6;

  if (tid < 64) {
    size_t n = (size_t)tid * TT + t;
    sP[tid] = smin_p[n]; izP[tid] = iz2_p[n];
    sQ[tid] = smin_q[n]; lzQ[tid] = lz1_q[n];
  }
  __syncthreads();

  #pragma unroll
  for (int i = 0; i < 16; ++i) {
    int b = i * 4 + wq;
    size_t n = (size_t)b * TT + t;
    float dp = Dp[n * MCB + lm];
    PA[0][lm][b] = __expf(-2.f * (sqrtf(fmaxf(dp, 0.f)) - sP[b]));
    float dq = Dq[n * MCB + lm];
    WQ[0][lm][b] = sqrtf(fmaxf(dq, 0.f)) - sQ[b];
  }
  __syncthreads();

  float acc[4][4] = {};
  for (int ch = 0; ch < 16; ++ch) {
    const int cur = ch & 1;
    if (ch < 15) {
      const int mc = (ch + 1) * 64;
      #pragma unroll
      for (int i = 0; i < 16; ++i) {
        int b = i * 4 + wq;
        size_t n = (size_t)b * TT + t;
        float dp = Dp[n * MCB + mc + lm];
        PA[cur ^ 1][lm][b] = __expf(-2.f * (sqrtf(fmaxf(dp, 0.f)) - sP[b]));
        float dq = Dq[n * MCB + mc + lm];
        WQ[cur ^ 1][lm][b] = sqrtf(fmaxf(dq, 0.f)) - sQ[b];
      }
    }
    #pragma unroll
    for (int mm = 0; mm < 64; ++mm) {
      float4 av = *(const float4*)(&PA[cur][mm][ty << 2]);
      float4 bv = *(const float4*)(&WQ[cur][mm][tx << 2]);
      float aa[4] = {av.x, av.y, av.z, av.w};
      float bb[4] = {bv.x, bv.y, bv.z, bv.w};
      #pragma unroll
      for (int i = 0; i < 4; ++i)
        #pragma unroll
        for (int j = 0; j < 4; ++j)
          acc[i][j] = fmaf(aa[i], bb[j], acc[i][j]);
    }
    __syncthreads();
  }

  float mn = 3.4e38f;
  #pragma unroll
  for (int i = 0; i < 4; ++i) {
    float izb = izP[(ty << 2) + i];
    float o[4];
    #pragma unroll
    for (int j = 0; j < 4; ++j) {
      o[j] = -izb * acc[i][j] - lzQ[(tx << 2) + j];
      mn = fminf(mn, o[j]);
    }
    *(float4*)(S + ((size_t)t * 64 + (ty << 2) + i) * 64 + (tx << 2)) =
        *(const float4*)(&o[0]);
  }
  #pragma unroll
  for (int off = 32; off; off >>= 1) mn = fminf(mn, __shfl_xor(mn, off));
  const int lane = tid & 63;
  if (lane == 0) redmin[wq] = mn;
  __syncthreads();
  if (tid == 0)
    part[z * 128 + t] =
        fminf(fminf(redmin[0], redmin[1]), fminf(redmin[2], redmin[3]));
}

// ---------------------------------------------------------------------------
// Kernel 5: final max(-S) per tensor
__global__ void k_sfinal(float* __restrict__ ws) {
  const float* part = ws + OFF_PART;
  float* maxv = ws + OFF_MAX;
  const int tens = threadIdx.x >> 7;
  const int i = threadIdx.x & 127;
  float m = part[tens * 128 + i];
  #pragma unroll
  for (int off = 32; off; off >>= 1) m = fminf(m, __shfl_xor(m, off));
  __shared__ float red[4];
  const int lane = threadIdx.x & 63, wid = threadIdx.x >> 6;
  if (lane == 0) red[wid] = m;
  __syncthreads();
  if (threadIdx.x == 0)   maxv[0] = -fminf(red[0], red[1]);
  if (threadIdx.x == 128) maxv[1] = -fminf(red[2], red[3]);
}

// ---------------------------------------------------------------------------
// Kernel 6: loss rows; per-wave register accumulation, per-block partial.
__global__ __launch_bounds__(256) void k_loss(float* __restrict__ ws) {
  const int lane = threadIdx.x & 63, wid = threadIdx.x >> 6;
  const int wglobal = blockIdx.x * 4 + wid;   // 0..1023
  const float* Smax = ws + OFF_MAX;
  double acc = 0.0;
  #pragma unroll 4
  for (int r = 0; r < 16; ++r) {
    int gw = wglobal * 16 + r;                // 0..16383
    int tens = gw >> 13;
    int rem = gw & 8191;                      // t*64 + b
    const float* S = ws + (tens ? OFF_S2 : OFF_S1);
    float maxv = Smax[tens];
    float ev = __expf(S[(size_t)rem * 64 + lane] + maxv);
    float sum = ev;
    #pragma unroll
    for (int off = 32; off; off >>= 1) sum += __shfl_xor(sum, off);
    float diag = __shfl(ev, rem & 63);
    if (lane == 0) acc += (double)__logf(diag / (sum + 1e-5f));
  }
  __shared__ double red[4];
  if (lane == 0) red[wid] = acc;
  __syncthreads();
  if (threadIdx.x == 0)
    ((double*)(ws + OFF_PACC))[blockIdx.x] = red[0] + red[1] + red[2] + red[3];
}

// Kernel 7: reduce 256 per-block partials, finalize loss
__global__ void k_fin(const float* __restrict__ ws, float* __restrict__ out) {
  const double* p = (const double*)(ws + OFF_PACC);
  const int lane = threadIdx.x & 63, wid = threadIdx.x >> 6;
  double v = p[threadIdx.x];
  #pragma unroll
  for (int off = 32; off; off >>= 1) v += __shfl_xor(v, off);
  __shared__ double red[4];
  if (lane == 0) red[wid] = v;
  __syncthreads();
  if (threadIdx.x == 0)
    out[0] = (float)(-(red[0] + red[1] + red[2] + red[3]) / 16384.0);
}

// ---------------------------------------------------------------------------
extern "C" void kernel_launch(void* const* d_in, const int* in_sizes, int n_in,
                              void* d_out, int out_size, void* d_ws, size_t ws_size,
                              hipStream_t stream) {
  const float* A = (const float*)d_in[0];
  const float* V = (const float*)d_in[1];
  const float* E = (const float*)d_in[2];
  float* out = (float*)d_out;
  float* ws  = (float*)d_ws;

  k_sumsq  <<<dim3(4352), dim3(256), 0, stream>>>(A, V, E, ws);
  k_dist   <<<dim3(8, 64, 2), dim3(256), 0, stream>>>(A, V, E, ws);
  k_rowstats<<<dim3(2048, 2), dim3(256), 0, stream>>>(A, V, E, ws, out);
  k_sgemm  <<<dim3(128, 2), dim3(256), 0, stream>>>(ws);
  k_sfinal <<<dim3(1), dim3(256), 0, stream>>>(ws);
  k_loss   <<<dim3(256), dim3(256), 0, stream>>>(ws);
  k_fin    <<<dim3(1), dim3(256), 0, stream>>>(ws, out);
}

// Round 11
// 102.683 us; speedup vs baseline: 6.5340x; 1.4897x over previous
//
#include <hip/hip_runtime.h>

// Problem sizes
#define NROWS 8192   // B*T
#define MCB   1024   // codebook size M
#define DD    256    // feature dim D
#define TT    128    // T
#define BB    64     // B

// ws offsets (in floats)
#define OFF_DA      0ul
#define OFF_DV      8388608ul
#define OFF_XX_A    16777216ul
#define OFF_XX_V    16785408ul
#define OFF_EE      16793600ul
#define OFF_SMIN_A  16794624ul
#define OFF_LZ1_A   16802816ul
#define OFF_IZ2_A   16811008ul
#define OFF_IDX_A   16819200ul
#define OFF_SMIN_V  16827392ul
#define OFF_LZ1_V   16835584ul
#define OFF_IZ2_V   16843776ul
#define OFF_IDX_V   16851968ul
#define OFF_S1      16860160ul
#define OFF_S2      17384448ul
#define OFF_PART    17908736ul
#define OFF_MAX     17908992ul
#define OFF_PACC    17909000ul   // 256 doubles, per-block loss partials
// split-bf16 planes (ushort arrays), 16B-aligned float offsets:
#define OFF_HIA     17909504ul   // 8192*256 ushorts = 1048576 floats
#define OFF_LOA     (OFF_HIA + 1048576ul)
#define OFF_HIV     (OFF_HIA + 2097152ul)
#define OFF_LOV     (OFF_HIA + 3145728ul)
#define OFF_HIE     (OFF_HIA + 4194304ul)   // 1024*256 ushorts = 131072 floats
#define OFF_LOE     (OFF_HIE + 131072ul)
// total ~22,366,000 floats ~ 89.5 MB of ws

typedef __attribute__((ext_vector_type(8))) short bf16x8;
typedef __attribute__((ext_vector_type(4))) float f32x4;

// ---------------------------------------------------------------------------
__device__ __forceinline__ void gload_lds16u(const ushort* gsrc, ushort* ldst) {
  __builtin_amdgcn_global_load_lds(
      (const __attribute__((address_space(1))) void*)gsrc,
      (__attribute__((address_space(3))) void*)ldst, 16, 0, 0);
}
__device__ __forceinline__ ushort bf16_rne(float x) {
  unsigned u = __float_as_uint(x);
  unsigned r = u + 0x7FFFu + ((u >> 16) & 1u);
  return (ushort)(r >> 16);
}
__device__ __forceinline__ float bf16_f(ushort h) {
  return __uint_as_float((unsigned)h << 16);
}

// ---------------------------------------------------------------------------
// Kernel 1: row sums of squares (fp64 accumulate) + split-bf16 hi/lo planes.
__global__ void k_sumsq(const float* __restrict__ A, const float* __restrict__ V,
                        const float* __restrict__ E, float* __restrict__ ws) {
  const int lane = threadIdx.x & 63;
  const int wid  = threadIdx.x >> 6;
  const int row = blockIdx.x * 4 + wid;   // 0..17407
  const float* src; float* dst; ushort* hi; ushort* lo; int r;
  if (row < 8192)       { src = A; r = row;         dst = ws + OFF_XX_A;
                          hi = (ushort*)(ws + OFF_HIA); lo = (ushort*)(ws + OFF_LOA); }
  else if (row < 16384) { src = V; r = row - 8192;  dst = ws + OFF_XX_V;
                          hi = (ushort*)(ws + OFF_HIV); lo = (ushort*)(ws + OFF_LOV); }
  else                  { src = E; r = row - 16384; dst = ws + OFF_EE;
                          hi = (ushort*)(ws + OFF_HIE); lo = (ushort*)(ws + OFF_LOE); }
  float4 x = *(const float4*)(src + (size_t)r * DD + lane * 4);
  ushort4 h, l;
  h.x = bf16_rne(x.x); l.x = bf16_rne(x.x - bf16_f(h.x));
  h.y = bf16_rne(x.y); l.y = bf16_rne(x.y - bf16_f(h.y));
  h.z = bf16_rne(x.z); l.z = bf16_rne(x.z - bf16_f(h.z));
  h.w = bf16_rne(x.w); l.w = bf16_rne(x.w - bf16_f(h.w));
  *(ushort4*)(hi + (size_t)r * DD + lane * 4) = h;
  *(ushort4*)(lo + (size_t)r * DD + lane * 4) = l;
  double acc = (double)x.x * x.x + (double)x.y * x.y +
               (double)x.z * x.z + (double)x.w * x.w;
  #pragma unroll
  for (int off = 32; off; off >>= 1) acc += __shfl_xor(acc, off);
  if (lane == 0) dst[r] = (float)acc;
}

// ---------------------------------------------------------------------------
// Kernel 2: dist GEMM via split-bf16 MFMA (hi*hi + hi*lo + lo*hi).
// (round-10 structure, unchanged — verified absmax 0.0)
__global__ __launch_bounds__(256) void k_dist(const float* __restrict__ A,
    const float* __restrict__ V, const float* __restrict__ E,
    float* __restrict__ ws) {
  const int z = blockIdx.z;
  const ushort* Xhi = (const ushort*)(ws + (z ? OFF_HIV : OFF_HIA));
  const ushort* Xlo = (const ushort*)(ws + (z ? OFF_LOV : OFF_LOA));
  const ushort* Ehi = (const ushort*)(ws + OFF_HIE);
  const ushort* Elo = (const ushort*)(ws + OFF_LOE);
  const float* xx = ws + (z ? OFF_XX_V : OFF_XX_A);
  const float* ee = ws + OFF_EE;
  float* Dst = ws + (z ? OFF_DV : OFF_DA);

  __shared__ __align__(16) ushort LAhi[128 * 32];
  __shared__ __align__(16) ushort LAlo[128 * 32];
  __shared__ __align__(16) ushort LBhi[128 * 32];
  __shared__ __align__(16) ushort LBlo[128 * 32];

  const int tid = threadIdx.x;
  const int bid = blockIdx.y * 8 + blockIdx.x;        // 0..511
  const int sw  = (bid & 7) * 64 + (bid >> 3);
  const int colb = sw & 7, rowb = sw >> 3;
  const int row0 = rowb * 128;
  const int col0 = colb * 128;

  const int wv = tid >> 6, lane = tid & 63;
  const int wr = wv >> 1, wc = wv & 1;                // wave tile (64x64)
  const int rl = lane & 15, kg = lane >> 4;

  const int c0 = tid, c1 = 256 + tid;
  const int r0 = c0 >> 2, lg0 = (c0 & 3) ^ ((r0 >> 1) & 3);
  const int r1 = c1 >> 2, lg1 = (c1 & 3) ^ ((r1 >> 1) & 3);
  const ushort* gAhi0 = Xhi + (size_t)(row0 + r0) * DD + lg0 * 8;
  const ushort* gAhi1 = Xhi + (size_t)(row0 + r1) * DD + lg1 * 8;
  const ushort* gAlo0 = Xlo + (size_t)(row0 + r0) * DD + lg0 * 8;
  const ushort* gAlo1 = Xlo + (size_t)(row0 + r1) * DD + lg1 * 8;
  const ushort* gBhi0 = Ehi + (size_t)(col0 + r0) * DD + lg0 * 8;
  const ushort* gBhi1 = Ehi + (size_t)(col0 + r1) * DD + lg1 * 8;
  const ushort* gBlo0 = Elo + (size_t)(col0 + r0) * DD + lg0 * 8;
  const ushort* gBlo1 = Elo + (size_t)(col0 + r1) * DD + lg1 * 8;
  const int d0 = c0 * 8, d1 = c1 * 8;

  int aidx[4], bidx[4];
  #pragma unroll
  for (int f = 0; f < 4; ++f) {
    int ra = wr * 64 + f * 16 + rl;
    aidx[f] = ra * 32 + ((kg ^ ((ra >> 1) & 3)) << 3);
    int rb = wc * 64 + f * 16 + rl;
    bidx[f] = rb * 32 + ((kg ^ ((rb >> 1) & 3)) << 3);
  }

  f32x4 acc[4][4] = {};

  for (int t = 0; t < 8; ++t) {
    const int kc = t * 32;
    gload_lds16u(gAhi0 + kc, &LAhi[d0]);
    gload_lds16u(gAhi1 + kc, &LAhi[d1]);
    gload_lds16u(gAlo0 + kc, &LAlo[d0]);
    gload_lds16u(gAlo1 + kc, &LAlo[d1]);
    gload_lds16u(gBhi0 + kc, &LBhi[d0]);
    gload_lds16u(gBhi1 + kc, &LBhi[d1]);
    gload_lds16u(gBlo0 + kc, &LBlo[d0]);
    gload_lds16u(gBlo1 + kc, &LBlo[d1]);
    __syncthreads();
    __builtin_amdgcn_s_setprio(1);
    bf16x8 ahi[4], alo[4], bhi[4], blo[4];
    #pragma unroll
    for (int f = 0; f < 4; ++f) {
      ahi[f] = *(const bf16x8*)(&LAhi[aidx[f]]);
      alo[f] = *(const bf16x8*)(&LAlo[aidx[f]]);
      bhi[f] = *(const bf16x8*)(&LBhi[bidx[f]]);
      blo[f] = *(const bf16x8*)(&LBlo[bidx[f]]);
    }
    #pragma unroll
    for (int fr = 0; fr < 4; ++fr)
      #pragma unroll
      for (int fc = 0; fc < 4; ++fc) {
        acc[fr][fc] = __builtin_amdgcn_mfma_f32_16x16x32_bf16(
            ahi[fr], bhi[fc], acc[fr][fc], 0, 0, 0);
        acc[fr][fc] = __builtin_amdgcn_mfma_f32_16x16x32_bf16(
            ahi[fr], blo[fc], acc[fr][fc], 0, 0, 0);
        acc[fr][fc] = __builtin_amdgcn_mfma_f32_16x16x32_bf16(
            alo[fr], bhi[fc], acc[fr][fc], 0, 0, 0);
      }
    __builtin_amdgcn_s_setprio(0);
    __syncthreads();
  }

  float xn[4][4];
  #pragma unroll
  for (int fr = 0; fr < 4; ++fr)
    #pragma unroll
    for (int v = 0; v < 4; ++v)
      xn[fr][v] = xx[row0 + wr * 64 + fr * 16 + kg * 4 + v];
  #pragma unroll
  for (int fc = 0; fc < 4; ++fc) {
    const int m = col0 + wc * 64 + fc * 16 + rl;
    const float em = ee[m];
    #pragma unroll
    for (int fr = 0; fr < 4; ++fr) {
      #pragma unroll
      for (int v = 0; v < 4; ++v) {
        const int n = row0 + wr * 64 + fr * 16 + kg * 4 + v;
        Dst[(size_t)n * MCB + m] = (em + xn[fr][v]) - 2.0f * acc[fr][fc][v];
      }
    }
  }
}

// ---------------------------------------------------------------------------
// Kernel 3: per-row stats (min/argmin, softmax denominators) + quantize write.
__global__ void k_rowstats(const float* __restrict__ A, const float* __restrict__ V,
                           const float* __restrict__ E, float* __restrict__ ws,
                           float* __restrict__ out) {
  const int z = blockIdx.y;
  const float* Dm = ws + (z ? OFF_DV : OFF_DA);
  const float* X  = z ? V : A;
  float* smin_o = ws + (z ? OFF_SMIN_V : OFF_SMIN_A);
  float* lz1_o  = ws + (z ? OFF_LZ1_V  : OFF_LZ1_A);
  float* iz2_o  = ws + (z ? OFF_IZ2_V  : OFF_IZ2_A);
  int*   idx_o  = (int*)(ws + (z ? OFF_IDX_V : OFF_IDX_A));
  float* qout = out + 1 + (size_t)z * ((size_t)NROWS * DD);

  const int lane = threadIdx.x & 63, wid = threadIdx.x >> 6;
  const int n = blockIdx.x * 4 + wid;
  const float* drow = Dm + (size_t)n * MCB;

  float v[16];
  #pragma unroll
  for (int c = 0; c < 4; ++c) {
    float4 t = *(const float4*)(drow + c * 256 + lane * 4);
    v[c*4+0] = t.x; v[c*4+1] = t.y; v[c*4+2] = t.z; v[c*4+3] = t.w;
  }
  float bv = 3.4e38f; int bi = 0;
  #pragma unroll
  for (int c = 0; c < 4; ++c)
    #pragma unroll
    for (int j = 0; j < 4; ++j) {
      float val = v[c*4+j];
      int m = c * 256 + lane * 4 + j;
      if (val < bv) { bv = val; bi = m; }
    }
  #pragma unroll
  for (int off = 32; off; off >>= 1) {
    float ov = __shfl_xor(bv, off);
    int   oi = __shfl_xor(bi, off);
    if (ov < bv || (ov == bv && oi < bi)) { bv = ov; bi = oi; }
  }
  float smin = sqrtf(fmaxf(bv, 0.0f));
  float z1 = 0.f, z2 = 0.f;
  #pragma unroll
  for (int q = 0; q < 16; ++q) {
    float w = sqrtf(fmaxf(v[q], 0.0f)) - smin;
    z1 += __expf(-w);
    z2 += __expf(-2.0f * w);
  }
  #pragma unroll
  for (int off = 32; off; off >>= 1) {
    z1 += __shfl_xor(z1, off);
    z2 += __shfl_xor(z2, off);
  }
  if (lane == 0) {
    smin_o[n] = smin;
    lz1_o[n]  = __logf(z1);
    iz2_o[n]  = 1.0f / z2;
    idx_o[n]  = bi;
  }
  const float* erow = E + (size_t)bi * DD;
  const float* xrow = X + (size_t)n * DD;
  #pragma unroll
  for (int p = 0; p < 4; ++p) {
    int dd = p * 64 + lane;
    float xv = xrow[dd];
    float ev = erow[dd];
    qout[(size_t)n * DD + dd] = xv + (ev - xv);
  }
}

// ---------------------------------------------------------------------------
// Kernel 4 (MFMA): S[t,b,c] = -izP[b]*(sum_m pa[b,m]*wv[c,m]) - lzQ[c]
// pa = exp(-2*(sqrt(dp)-sP[b])), wv = sqrt(dq)-sQ[c]; both bf16 (loss path,
// threshold 8e-2; error ~2e-5). 512 threads = 8 waves: wave = (b-tile wv&3,
// c-half wv>>2); per m-chunk of 32: transform->LDS bf16 planes [64][32]
// (dbuf, 1 barrier/chunk, static 2-chunk unroll, reg-prefetch next chunk),
// 1 A-frag + 2 B-frags + 2 MFMA per wave. LDS aliasing at b64/b128 hw
// minimum (row stride 64 B) -> no swizzle needed. Fused epilogue + block-min.
__global__ __launch_bounds__(512) void k_sgemm(float* __restrict__ ws) {
  const int z = blockIdx.y;
  const int t = blockIdx.x;
  const float* Dp = ws + (z ? OFF_DV : OFF_DA);
  const float* Dq = ws + (z ? OFF_DA : OFF_DV);
  const float* smin_p = ws + (z ? OFF_SMIN_V : OFF_SMIN_A);
  const float* iz2_p  = ws + (z ? OFF_IZ2_V  : OFF_IZ2_A);
  const float* smin_q = ws + (z ? OFF_SMIN_A : OFF_SMIN_V);
  const float* lz1_q  = ws + (z ? OFF_LZ1_A  : OFF_LZ1_V);
  float* S = ws + (z ? OFF_S2 : OFF_S1);
  float* part = ws + OFF_PART;

  __shared__ __align__(16) ushort PAs[2][64][32];
  __shared__ __align__(16) ushort WQs[2][64][32];
  __shared__ float sP[64], izP[64], sQ[64], lzQ[64];
  __shared__ float redmin[8];

  const int tid = threadIdx.x;
  const int wv = tid >> 6, lane = tid & 63;
  const int rl = lane & 15, kg = lane >> 4;
  const int bt  = (wv & 3) * 16;      // wave b-tile base
  const int ctl = (wv >> 2) * 32;     // wave c-half base

  if (tid < 64) {
    size_t n = (size_t)tid * TT + t;
    sP[tid] = smin_p[n]; izP[tid] = iz2_p[n];
    sQ[tid] = smin_q[n]; lzQ[tid] = lz1_q[n];
  }
  __syncthreads();

  // staging: thread -> (row sb, m-offset sm); 4 p + 4 q transforms per chunk
  const int sb = tid >> 3;            // 0..63
  const int sm = (tid & 7) * 4;       // 0,4,..,28
  const float sPb = sP[sb], sQb = sQ[sb];
  const float* dpb = Dp + (size_t)(sb * TT + t) * MCB + sm;
  const float* dqb = Dq + (size_t)(sb * TT + t) * MCB + sm;

#define XF(rp, rq, buf) { \
    ushort4 hp, hq; \
    hp.x = bf16_rne(__expf(-2.f * (sqrtf(fmaxf((rp).x, 0.f)) - sPb))); \
    hp.y = bf16_rne(__expf(-2.f * (sqrtf(fmaxf((rp).y, 0.f)) - sPb))); \
    hp.z = bf16_rne(__expf(-2.f * (sqrtf(fmaxf((rp).z, 0.f)) - sPb))); \
    hp.w = bf16_rne(__expf(-2.f * (sqrtf(fmaxf((rp).w, 0.f)) - sPb))); \
    hq.x = bf16_rne(sqrtf(fmaxf((rq).x, 0.f)) - sQb); \
    hq.y = bf16_rne(sqrtf(fmaxf((rq).y, 0.f)) - sQb); \
    hq.z = bf16_rne(sqrtf(fmaxf((rq).z, 0.f)) - sQb); \
    hq.w = bf16_rne(sqrtf(fmaxf((rq).w, 0.f)) - sQb); \
    *(ushort4*)(&PAs[buf][sb][sm]) = hp; \
    *(ushort4*)(&WQs[buf][sb][sm]) = hq; }

#define MM(buf) { \
    bf16x8 af = *(const bf16x8*)(&PAs[buf][bt + rl][kg * 8]); \
    bf16x8 b0 = *(const bf16x8*)(&WQs[buf][ctl + rl][kg * 8]); \
    bf16x8 b1 = *(const bf16x8*)(&WQs[buf][ctl + 16 + rl][kg * 8]); \
    acc0 = __builtin_amdgcn_mfma_f32_16x16x32_bf16(af, b0, acc0, 0, 0, 0); \
    acc1 = __builtin_amdgcn_mfma_f32_16x16x32_bf16(af, b1, acc1, 0, 0, 0); }

  f32x4 acc0 = {}, acc1 = {};
  float4 rpA, rqA, rpB, rqB;

  rpA = *(const float4*)(dpb);        rqA = *(const float4*)(dqb);
  XF(rpA, rqA, 0)                     // chunk 0 -> LDS[0]
  rpB = *(const float4*)(dpb + 32);   rqB = *(const float4*)(dqb + 32);

  #pragma unroll 4
  for (int c2 = 0; c2 < 16; ++c2) {
    const int che = c2 * 2;
    __syncthreads();                  // LDS[0] (chunk che) ready
    if (che + 2 < 32) {
      rpA = *(const float4*)(dpb + (che + 2) * 32);
      rqA = *(const float4*)(dqb + (che + 2) * 32);
    }
    MM(0)
    XF(rpB, rqB, 1)                   // chunk che+1 -> LDS[1]
    __syncthreads();                  // LDS[1] ready
    if (che + 3 < 32) {
      rpB = *(const float4*)(dpb + (che + 3) * 32);
      rqB = *(const float4*)(dqb + (che + 3) * 32);
    }
    MM(1)
    if (che + 2 < 32) XF(rpA, rqA, 0) // chunk che+2 -> LDS[0]
  }
#undef XF
#undef MM

  // epilogue: S = -izP[b]*G - lzQ[c]; fused block-min
  float mn = 3.4e38f;
  #pragma unroll
  for (int v = 0; v < 4; ++v) {
    const int b = bt + kg * 4 + v;
    const float izb = izP[b];
    float s0 = -izb * acc0[v] - lzQ[ctl + rl];
    float s1 = -izb * acc1[v] - lzQ[ctl + 16 + rl];
    S[((size_t)t * 64 + b) * 64 + ctl + rl]      = s0;
    S[((size_t)t * 64 + b) * 64 + ctl + 16 + rl] = s1;
    mn = fminf(mn, fminf(s0, s1));
  }
  #pragma unroll
  for (int off = 32; off; off >>= 1) mn = fminf(mn, __shfl_xor(mn, off));
  if (lane == 0) redmin[wv] = mn;
  __syncthreads();
  if (tid == 0) {
    float m = redmin[0];
    #pragma unroll
    for (int i = 1; i < 8; ++i) m = fminf(m, redmin[i]);
    part[z * 128 + t] = m;
  }
}

// ---------------------------------------------------------------------------
// Kernel 5: final max(-S) per tensor
__global__ void k_sfinal(float* __restrict__ ws) {
  const float* part = ws + OFF_PART;
  float* maxv = ws + OFF_MAX;
  const int tens = threadIdx.x >> 7;
  const int i = threadIdx.x & 127;
  float m = part[tens * 128 + i];
  #pragma unroll
  for (int off = 32; off; off >>= 1) m = fminf(m, __shfl_xor(m, off));
  __shared__ float red[4];
  const int lane = threadIdx.x & 63, wid = threadIdx.x >> 6;
  if (lane == 0) red[wid] = m;
  __syncthreads();
  if (threadIdx.x == 0)   maxv[0] = -fminf(red[0], red[1]);
  if (threadIdx.x == 128) maxv[1] = -fminf(red[2], red[3]);
}

// ---------------------------------------------------------------------------
// Kernel 6: loss rows; per-wave register accumulation, per-block partial.
__global__ __launch_bounds__(256) void k_loss(float* __restrict__ ws) {
  const int lane = threadIdx.x & 63, wid = threadIdx.x >> 6;
  const int wglobal = blockIdx.x * 4 + wid;   // 0..1023
  const float* Smax = ws + OFF_MAX;
  double acc = 0.0;
  #pragma unroll 4
  for (int r = 0; r < 16; ++r) {
    int gw = wglobal * 16 + r;                // 0..16383
    int tens = gw >> 13;
    int rem = gw & 8191;                      // t*64 + b
    const float* S = ws + (tens ? OFF_S2 : OFF_S1);
    float maxv = Smax[tens];
    float ev = __expf(S[(size_t)rem * 64 + lane] + maxv);
    float sum = ev;
    #pragma unroll
    for (int off = 32; off; off >>= 1) sum += __shfl_xor(sum, off);
    float diag = __shfl(ev, rem & 63);
    if (lane == 0) acc += (double)__logf(diag / (sum + 1e-5f));
  }
  __shared__ double red[4];
  if (lane == 0) red[wid] = acc;
  __syncthreads();
  if (threadIdx.x == 0)
    ((double*)(ws + OFF_PACC))[blockIdx.x] = red[0] + red[1] + red[2] + red[3];
}

// Kernel 7: reduce 256 per-block partials, finalize loss
__global__ void k_fin(const float* __restrict__ ws, float* __restrict__ out) {
  const double* p = (const double*)(ws + OFF_PACC);
  const int lane = threadIdx.x & 63, wid = threadIdx.x >> 6;
  double v = p[threadIdx.x];
  #pragma unroll
  for (int off = 32; off; off >>= 1) v += __shfl_xor(v, off);
  __shared__ double red[4];
  if (lane == 0) red[wid] = v;
  __syncthreads();
  if (threadIdx.x == 0)
    out[0] = (float)(-(red[0] + red[1] + red[2] + red[3]) / 16384.0);
}

// ---------------------------------------------------------------------------
extern "C" void kernel_launch(void* const* d_in, const int* in_sizes, int n_in,
                              void* d_out, int out_size, void* d_ws, size_t ws_size,
                              hipStream_t stream) {
  const float* A = (const float*)d_in[0];
  const float* V = (const float*)d_in[1];
  const float* E = (const float*)d_in[2];
  float* out = (float*)d_out;
  float* ws  = (float*)d_ws;

  k_sumsq  <<<dim3(4352), dim3(256), 0, stream>>>(A, V, E, ws);
  k_dist   <<<dim3(8, 64, 2), dim3(256), 0, stream>>>(A, V, E, ws);
  k_rowstats<<<dim3(2048, 2), dim3(256), 0, stream>>>(A, V, E, ws, out);
  k_sgemm  <<<dim3(128, 2), dim3(512), 0, stream>>>(ws);
  k_sfinal <<<dim3(1), dim3(256), 0, stream>>>(ws);
  k_loss   <<<dim3(256), dim3(256), 0, stream>>>(ws);
  k_fin    <<<dim3(1), dim3(256), 0, stream>>>(ws, out);
}

// Round 12
// 98.537 us; speedup vs baseline: 6.8090x; 1.0421x over previous
//
#include <hip/hip_runtime.h>

// Problem sizes
#define NROWS 8192   // B*T
#define MCB   1024   // codebook size M
#define DD    256    // feature dim D
#define TT    128    // T
#define BB    64     // B

// ws offsets (in floats)
#define OFF_DA      0ul
#define OFF_DV      8388608ul
#define OFF_XX_A    16777216ul
#define OFF_XX_V    16785408ul
#define OFF_EE      16793600ul
#define OFF_SMIN_A  16794624ul
#define OFF_LZ1_A   16802816ul
#define OFF_IZ2_A   16811008ul
#define OFF_IDX_A   16819200ul
#define OFF_SMIN_V  16827392ul
#define OFF_LZ1_V   16835584ul
#define OFF_IZ2_V   16843776ul
#define OFF_IDX_V   16851968ul
#define OFF_S1      16860160ul
#define OFF_S2      17384448ul
#define OFF_PART    17908736ul
#define OFF_MAX     17908992ul
#define OFF_PACC    17909000ul   // 256 doubles, per-block loss partials
// split-bf16 planes (ushort arrays), 16B-aligned float offsets:
#define OFF_HIA     17909504ul   // 8192*256 ushorts = 1048576 floats
#define OFF_LOA     (OFF_HIA + 1048576ul)
#define OFF_HIV     (OFF_HIA + 2097152ul)
#define OFF_LOV     (OFF_HIA + 3145728ul)
#define OFF_HIE     (OFF_HIA + 4194304ul)   // 1024*256 ushorts = 131072 floats
#define OFF_LOE     (OFF_HIE + 131072ul)
// total ~22,366,000 floats ~ 89.5 MB of ws
// NOTE: after k_rowstats, the D rows are overwritten in place with bf16
// planes: row n = [ pa[1024] | wv[1024] ] ushorts (pa=exp(-2w), wv=w).

typedef __attribute__((ext_vector_type(8))) short bf16x8;
typedef __attribute__((ext_vector_type(4))) float f32x4;

// ---------------------------------------------------------------------------
__device__ __forceinline__ void gload_lds16u(const ushort* gsrc, ushort* ldst) {
  __builtin_amdgcn_global_load_lds(
      (const __attribute__((address_space(1))) void*)gsrc,
      (__attribute__((address_space(3))) void*)ldst, 16, 0, 0);
}
__device__ __forceinline__ ushort bf16_rne(float x) {
  unsigned u = __float_as_uint(x);
  unsigned r = u + 0x7FFFu + ((u >> 16) & 1u);
  return (ushort)(r >> 16);
}
__device__ __forceinline__ float bf16_f(ushort h) {
  return __uint_as_float((unsigned)h << 16);
}

// ---------------------------------------------------------------------------
// Kernel 1: row sums of squares (fp64 accumulate) + split-bf16 hi/lo planes.
__global__ void k_sumsq(const float* __restrict__ A, const float* __restrict__ V,
                        const float* __restrict__ E, float* __restrict__ ws) {
  const int lane = threadIdx.x & 63;
  const int wid  = threadIdx.x >> 6;
  const int row = blockIdx.x * 4 + wid;   // 0..17407
  const float* src; float* dst; ushort* hi; ushort* lo; int r;
  if (row < 8192)       { src = A; r = row;         dst = ws + OFF_XX_A;
                          hi = (ushort*)(ws + OFF_HIA); lo = (ushort*)(ws + OFF_LOA); }
  else if (row < 16384) { src = V; r = row - 8192;  dst = ws + OFF_XX_V;
                          hi = (ushort*)(ws + OFF_HIV); lo = (ushort*)(ws + OFF_LOV); }
  else                  { src = E; r = row - 16384; dst = ws + OFF_EE;
                          hi = (ushort*)(ws + OFF_HIE); lo = (ushort*)(ws + OFF_LOE); }
  float4 x = *(const float4*)(src + (size_t)r * DD + lane * 4);
  ushort4 h, l;
  h.x = bf16_rne(x.x); l.x = bf16_rne(x.x - bf16_f(h.x));
  h.y = bf16_rne(x.y); l.y = bf16_rne(x.y - bf16_f(h.y));
  h.z = bf16_rne(x.z); l.z = bf16_rne(x.z - bf16_f(h.z));
  h.w = bf16_rne(x.w); l.w = bf16_rne(x.w - bf16_f(h.w));
  *(ushort4*)(hi + (size_t)r * DD + lane * 4) = h;
  *(ushort4*)(lo + (size_t)r * DD + lane * 4) = l;
  double acc = (double)x.x * x.x + (double)x.y * x.y +
               (double)x.z * x.z + (double)x.w * x.w;
  #pragma unroll
  for (int off = 32; off; off >>= 1) acc += __shfl_xor(acc, off);
  if (lane == 0) dst[r] = (float)acc;
}

// ---------------------------------------------------------------------------
// Kernel 2: dist GEMM via split-bf16 MFMA (hi*hi + hi*lo + lo*hi).
// (round-10 structure, unchanged — verified absmax 0.0)
__global__ __launch_bounds__(256) void k_dist(const float* __restrict__ A,
    const float* __restrict__ V, const float* __restrict__ E,
    float* __restrict__ ws) {
  const int z = blockIdx.z;
  const ushort* Xhi = (const ushort*)(ws + (z ? OFF_HIV : OFF_HIA));
  const ushort* Xlo = (const ushort*)(ws + (z ? OFF_LOV : OFF_LOA));
  const ushort* Ehi = (const ushort*)(ws + OFF_HIE);
  const ushort* Elo = (const ushort*)(ws + OFF_LOE);
  const float* xx = ws + (z ? OFF_XX_V : OFF_XX_A);
  const float* ee = ws + OFF_EE;
  float* Dst = ws + (z ? OFF_DV : OFF_DA);

  __shared__ __align__(16) ushort LAhi[128 * 32];
  __shared__ __align__(16) ushort LAlo[128 * 32];
  __shared__ __align__(16) ushort LBhi[128 * 32];
  __shared__ __align__(16) ushort LBlo[128 * 32];

  const int tid = threadIdx.x;
  const int bid = blockIdx.y * 8 + blockIdx.x;        // 0..511
  const int sw  = (bid & 7) * 64 + (bid >> 3);
  const int colb = sw & 7, rowb = sw >> 3;
  const int row0 = rowb * 128;
  const int col0 = colb * 128;

  const int wv = tid >> 6, lane = tid & 63;
  const int wr = wv >> 1, wc = wv & 1;                // wave tile (64x64)
  const int rl = lane & 15, kg = lane >> 4;

  const int c0 = tid, c1 = 256 + tid;
  const int r0 = c0 >> 2, lg0 = (c0 & 3) ^ ((r0 >> 1) & 3);
  const int r1 = c1 >> 2, lg1 = (c1 & 3) ^ ((r1 >> 1) & 3);
  const ushort* gAhi0 = Xhi + (size_t)(row0 + r0) * DD + lg0 * 8;
  const ushort* gAhi1 = Xhi + (size_t)(row0 + r1) * DD + lg1 * 8;
  const ushort* gAlo0 = Xlo + (size_t)(row0 + r0) * DD + lg0 * 8;
  const ushort* gAlo1 = Xlo + (size_t)(row0 + r1) * DD + lg1 * 8;
  const ushort* gBhi0 = Ehi + (size_t)(col0 + r0) * DD + lg0 * 8;
  const ushort* gBhi1 = Ehi + (size_t)(col0 + r1) * DD + lg1 * 8;
  const ushort* gBlo0 = Elo + (size_t)(col0 + r0) * DD + lg0 * 8;
  const ushort* gBlo1 = Elo + (size_t)(col0 + r1) * DD + lg1 * 8;
  const int d0 = c0 * 8, d1 = c1 * 8;

  int aidx[4], bidx[4];
  #pragma unroll
  for (int f = 0; f < 4; ++f) {
    int ra = wr * 64 + f * 16 + rl;
    aidx[f] = ra * 32 + ((kg ^ ((ra >> 1) & 3)) << 3);
    int rb = wc * 64 + f * 16 + rl;
    bidx[f] = rb * 32 + ((kg ^ ((rb >> 1) & 3)) << 3);
  }

  f32x4 acc[4][4] = {};

  for (int t = 0; t < 8; ++t) {
    const int kc = t * 32;
    gload_lds16u(gAhi0 + kc, &LAhi[d0]);
    gload_lds16u(gAhi1 + kc, &LAhi[d1]);
    gload_lds16u(gAlo0 + kc, &LAlo[d0]);
    gload_lds16u(gAlo1 + kc, &LAlo[d1]);
    gload_lds16u(gBhi0 + kc, &LBhi[d0]);
    gload_lds16u(gBhi1 + kc, &LBhi[d1]);
    gload_lds16u(gBlo0 + kc, &LBlo[d0]);
    gload_lds16u(gBlo1 + kc, &LBlo[d1]);
    __syncthreads();
    __builtin_amdgcn_s_setprio(1);
    bf16x8 ahi[4], alo[4], bhi[4], blo[4];
    #pragma unroll
    for (int f = 0; f < 4; ++f) {
      ahi[f] = *(const bf16x8*)(&LAhi[aidx[f]]);
      alo[f] = *(const bf16x8*)(&LAlo[aidx[f]]);
      bhi[f] = *(const bf16x8*)(&LBhi[bidx[f]]);
      blo[f] = *(const bf16x8*)(&LBlo[bidx[f]]);
    }
    #pragma unroll
    for (int fr = 0; fr < 4; ++fr)
      #pragma unroll
      for (int fc = 0; fc < 4; ++fc) {
        acc[fr][fc] = __builtin_amdgcn_mfma_f32_16x16x32_bf16(
            ahi[fr], bhi[fc], acc[fr][fc], 0, 0, 0);
        acc[fr][fc] = __builtin_amdgcn_mfma_f32_16x16x32_bf16(
            ahi[fr], blo[fc], acc[fr][fc], 0, 0, 0);
        acc[fr][fc] = __builtin_amdgcn_mfma_f32_16x16x32_bf16(
            alo[fr], bhi[fc], acc[fr][fc], 0, 0, 0);
      }
    __builtin_amdgcn_s_setprio(0);
    __syncthreads();
  }

  float xn[4][4];
  #pragma unroll
  for (int fr = 0; fr < 4; ++fr)
    #pragma unroll
    for (int v = 0; v < 4; ++v)
      xn[fr][v] = xx[row0 + wr * 64 + fr * 16 + kg * 4 + v];
  #pragma unroll
  for (int fc = 0; fc < 4; ++fc) {
    const int m = col0 + wc * 64 + fc * 16 + rl;
    const float em = ee[m];
    #pragma unroll
    for (int fr = 0; fr < 4; ++fr) {
      #pragma unroll
      for (int v = 0; v < 4; ++v) {
        const int n = row0 + wr * 64 + fr * 16 + kg * 4 + v;
        Dst[(size_t)n * MCB + m] = (em + xn[fr][v]) - 2.0f * acc[fr][fc][v];
      }
    }
  }
}

// ---------------------------------------------------------------------------
// Kernel 3: per-row stats (min/argmin, softmax denominators) + quantize write
// + IN-PLACE transform: overwrite the row's 4 KB with bf16 [pa[1024]|wv[1024]]
// (pa = exp(-2w), wv = w = sqrt(max(d,0))-smin) for k_sgemm's pure-GEMM path.
__global__ void k_rowstats(const float* __restrict__ A, const float* __restrict__ V,
                           const float* __restrict__ E, float* __restrict__ ws,
                           float* __restrict__ out) {
  const int z = blockIdx.y;
  float* Dm = ws + (z ? OFF_DV : OFF_DA);
  const float* X  = z ? V : A;
  float* smin_o = ws + (z ? OFF_SMIN_V : OFF_SMIN_A);
  float* lz1_o  = ws + (z ? OFF_LZ1_V  : OFF_LZ1_A);
  float* iz2_o  = ws + (z ? OFF_IZ2_V  : OFF_IZ2_A);
  int*   idx_o  = (int*)(ws + (z ? OFF_IDX_V : OFF_IDX_A));
  float* qout = out + 1 + (size_t)z * ((size_t)NROWS * DD);

  const int lane = threadIdx.x & 63, wid = threadIdx.x >> 6;
  const int n = blockIdx.x * 4 + wid;
  float* drow = Dm + (size_t)n * MCB;

  float v[16];
  #pragma unroll
  for (int c = 0; c < 4; ++c) {
    float4 t = *(const float4*)(drow + c * 256 + lane * 4);
    v[c*4+0] = t.x; v[c*4+1] = t.y; v[c*4+2] = t.z; v[c*4+3] = t.w;
  }
  float bv = 3.4e38f; int bi = 0;
  #pragma unroll
  for (int c = 0; c < 4; ++c)
    #pragma unroll
    for (int j = 0; j < 4; ++j) {
      float val = v[c*4+j];
      int m = c * 256 + lane * 4 + j;
      if (val < bv) { bv = val; bi = m; }
    }
  #pragma unroll
  for (int off = 32; off; off >>= 1) {
    float ov = __shfl_xor(bv, off);
    int   oi = __shfl_xor(bi, off);
    if (ov < bv || (ov == bv && oi < bi)) { bv = ov; bi = oi; }
  }
  float smin = sqrtf(fmaxf(bv, 0.0f));
  float w[16], e2[16];
  float z1 = 0.f, z2 = 0.f;
  #pragma unroll
  for (int q = 0; q < 16; ++q) {
    w[q] = sqrtf(fmaxf(v[q], 0.0f)) - smin;
    z1 += __expf(-w[q]);
    e2[q] = __expf(-2.0f * w[q]);
    z2 += e2[q];
  }
  #pragma unroll
  for (int off = 32; off; off >>= 1) {
    z1 += __shfl_xor(z1, off);
    z2 += __shfl_xor(z2, off);
  }
  if (lane == 0) {
    smin_o[n] = smin;
    lz1_o[n]  = __logf(z1);
    iz2_o[n]  = 1.0f / z2;
    idx_o[n]  = bi;
  }
  // in-place bf16 planes over the consumed row (wave owns row exclusively)
  ushort* prow = (ushort*)drow;
  #pragma unroll
  for (int c = 0; c < 4; ++c) {
    ushort4 hp, hw;
    hp.x = bf16_rne(e2[c*4+0]); hp.y = bf16_rne(e2[c*4+1]);
    hp.z = bf16_rne(e2[c*4+2]); hp.w = bf16_rne(e2[c*4+3]);
    hw.x = bf16_rne(w[c*4+0]);  hw.y = bf16_rne(w[c*4+1]);
    hw.z = bf16_rne(w[c*4+2]);  hw.w = bf16_rne(w[c*4+3]);
    *(ushort4*)(prow + c * 256 + lane * 4) = hp;
    *(ushort4*)(prow + 1024 + c * 256 + lane * 4) = hw;
  }
  const float* erow = E + (size_t)bi * DD;
  const float* xrow = X + (size_t)n * DD;
  #pragma unroll
  for (int p = 0; p < 4; ++p) {
    int dd = p * 64 + lane;
    float xv = xrow[dd];
    float ev = erow[dd];
    qout[(size_t)n * DD + dd] = xv + (ev - xv);
  }
}

// ---------------------------------------------------------------------------
// Kernel 4 (pure bf16 MFMA GEMM): S[t,b,c] = -izP[b]*(sum_m pa[b,m]*wv[c,m])
//                                            - lzQ[c]
// Planes pre-transformed by k_rowstats (bit-identical values to round 11).
// 512 threads = 8 waves (b-tile wv&3, c-half wv>>2); m-chunk 64, dbuf
// gload_lds, ONE barrier per chunk (prefetch next before compute).
// LDS [64][64] ushort with 16B-granule XOR swizzle key=row&7 both sides.
__global__ __launch_bounds__(512) void k_sgemm(float* __restrict__ ws) {
  const int z = blockIdx.y;
  const int t = blockIdx.x;
  const ushort* P = (const ushort*)(ws + (z ? OFF_DV : OFF_DA));  // pa rows
  const ushort* Q = (const ushort*)(ws + (z ? OFF_DA : OFF_DV));  // wv rows
  const float* iz2_p  = ws + (z ? OFF_IZ2_V  : OFF_IZ2_A);
  const float* lz1_q  = ws + (z ? OFF_LZ1_A  : OFF_LZ1_V);
  float* S = ws + (z ? OFF_S2 : OFF_S1);
  float* part = ws + OFF_PART;

  __shared__ __align__(16) ushort PAs[2][64 * 64];
  __shared__ __align__(16) ushort WQs[2][64 * 64];
  __shared__ float redmin[8];

  const int tid = threadIdx.x;
  const int wv = tid >> 6, lane = tid & 63;
  const int rl = lane & 15, kg = lane >> 4;
  const int bt  = (wv & 3) * 16;      // wave b-tile base
  const int ctl = (wv >> 2) * 32;     // wave c-half base

  // staging: granule c=tid (0..511): row sr=c>>3, phys slot sg=c&7 holds
  // logical granule sg^(sr&7); linear LDS dest tid*16B.
  const int sr = tid >> 3, sg = tid & 7;
  const int lg = sg ^ (sr & 7);
  const ushort* gP = P + (size_t)(sr * TT + t) * 2048 + lg * 8;
  const ushort* gQ = Q + (size_t)(sr * TT + t) * 2048 + 1024 + lg * 8;
  const int dso = tid * 8;

  // frag read offsets: logical granule g of row R at phys R*64+((g^(R&7))*8)
  const int ra = bt + rl;
  const int rb0 = ctl + rl, rb1 = ctl + 16 + rl;
  int aoff[2], b0off[2], b1off[2];
  #pragma unroll
  for (int ks = 0; ks < 2; ++ks) {
    int g = ks * 4 + kg;
    aoff[ks]  = ra  * 64 + ((g ^ (ra  & 7)) * 8);
    b0off[ks] = rb0 * 64 + ((g ^ (rb0 & 7)) * 8);
    b1off[ks] = rb1 * 64 + ((g ^ (rb1 & 7)) * 8);
  }

  f32x4 acc0 = {}, acc1 = {};

  gload_lds16u(gP, &PAs[0][dso]);
  gload_lds16u(gQ, &WQs[0][dso]);
  __syncthreads();

  for (int ch = 0; ch < 16; ++ch) {
    const int cur = ch & 1;
    if (ch < 15) {
      gload_lds16u(gP + (ch + 1) * 64, &PAs[cur ^ 1][dso]);
      gload_lds16u(gQ + (ch + 1) * 64, &WQs[cur ^ 1][dso]);
    }
    __builtin_amdgcn_s_setprio(1);
    #pragma unroll
    for (int ks = 0; ks < 2; ++ks) {
      bf16x8 af = *(const bf16x8*)(&PAs[cur][aoff[ks]]);
      bf16x8 b0 = *(const bf16x8*)(&WQs[cur][b0off[ks]]);
      bf16x8 b1 = *(const bf16x8*)(&WQs[cur][b1off[ks]]);
      acc0 = __builtin_amdgcn_mfma_f32_16x16x32_bf16(af, b0, acc0, 0, 0, 0);
      acc1 = __builtin_amdgcn_mfma_f32_16x16x32_bf16(af, b1, acc1, 0, 0, 0);
    }
    __builtin_amdgcn_s_setprio(0);
    __syncthreads();   // next chunk landed + this chunk fully read
  }

  // epilogue: S = -izP[b]*G - lzQ[c]; fused block-min
  const float lzq0 = lz1_q[(size_t)rb0 * TT + t];
  const float lzq1 = lz1_q[(size_t)rb1 * TT + t];
  float mn = 3.4e38f;
  #pragma unroll
  for (int v = 0; v < 4; ++v) {
    const int b = bt + kg * 4 + v;
    const float izb = iz2_p[(size_t)b * TT + t];
    float s0 = -izb * acc0[v] - lzq0;
    float s1 = -izb * acc1[v] - lzq1;
    S[((size_t)t * 64 + b) * 64 + rb0] = s0;
    S[((size_t)t * 64 + b) * 64 + rb1] = s1;
    mn = fminf(mn, fminf(s0, s1));
  }
  #pragma unroll
  for (int off = 32; off; off >>= 1) mn = fminf(mn, __shfl_xor(mn, off));
  if (lane == 0) redmin[wv] = mn;
  __syncthreads();
  if (tid == 0) {
    float m = redmin[0];
    #pragma unroll
    for (int i = 1; i < 8; ++i) m = fminf(m, redmin[i]);
    part[z * 128 + t] = m;
  }
}

// ---------------------------------------------------------------------------
// Kernel 5: final max(-S) per tensor
__global__ void k_sfinal(float* __restrict__ ws) {
  const float* part = ws + OFF_PART;
  float* maxv = ws + OFF_MAX;
  const int tens = threadIdx.x >> 7;
  const int i = threadIdx.x & 127;
  float m = part[tens * 128 + i];
  #pragma unroll
  for (int off = 32; off; off >>= 1) m = fminf(m, __shfl_xor(m, off));
  __shared__ float red[4];
  const int lane = threadIdx.x & 63, wid = threadIdx.x >> 6;
  if (lane == 0) red[wid] = m;
  __syncthreads();
  if (threadIdx.x == 0)   maxv[0] = -fminf(red[0], red[1]);
  if (threadIdx.x == 128) maxv[1] = -fminf(red[2], red[3]);
}

// ---------------------------------------------------------------------------
// Kernel 6: loss rows; per-wave register accumulation, per-block partial.
__global__ __launch_bounds__(256) void k_loss(float* __restrict__ ws) {
  const int lane = threadIdx.x & 63, wid = threadIdx.x >> 6;
  const int wglobal = blockIdx.x * 4 + wid;   // 0..1023
  const float* Smax = ws + OFF_MAX;
  double acc = 0.0;
  #pragma unroll 4
  for (int r = 0; r < 16; ++r) {
    int gw = wglobal * 16 + r;                // 0..16383
    int tens = gw >> 13;
    int rem = gw & 8191;                      // t*64 + b
    const float* S = ws + (tens ? OFF_S2 : OFF_S1);
    float maxv = Smax[tens];
    float ev = __expf(S[(size_t)rem * 64 + lane] + maxv);
    float sum = ev;
    #pragma unroll
    for (int off = 32; off; off >>= 1) sum += __shfl_xor(sum, off);
    float diag = __shfl(ev, rem & 63);
    if (lane == 0) acc += (double)__logf(diag / (sum + 1e-5f));
  }
  __shared__ double red[4];
  if (lane == 0) red[wid] = acc;
  __syncthreads();
  if (threadIdx.x == 0)
    ((double*)(ws + OFF_PACC))[blockIdx.x] = red[0] + red[1] + red[2] + red[3];
}

// Kernel 7: reduce 256 per-block partials, finalize loss
__global__ void k_fin(const float* __restrict__ ws, float* __restrict__ out) {
  const double* p = (const double*)(ws + OFF_PACC);
  const int lane = threadIdx.x & 63, wid = threadIdx.x >> 6;
  double v = p[threadIdx.x];
  #pragma unroll
  for (int off = 32; off; off >>= 1) v += __shfl_xor(v, off);
  __shared__ double red[4];
  if (lane == 0) red[wid] = v;
  __syncthreads();
  if (threadIdx.x == 0)
    out[0] = (float)(-(red[0] + red[1] + red[2] + red[3]) / 16384.0);
}

// ---------------------------------------------------------------------------
extern "C" void kernel_launch(void* const* d_in, const int* in_sizes, int n_in,
                              void* d_out, int out_size, void* d_ws, size_t ws_size,
                              hipStream_t stream) {
  const float* A = (const float*)d_in[0];
  const float* V = (const float*)d_in[1];
  const float* E = (const float*)d_in[2];
  float* out = (float*)d_out;
  float* ws  = (float*)d_ws;

  k_sumsq  <<<dim3(4352), dim3(256), 0, stream>>>(A, V, E, ws);
  k_dist   <<<dim3(8, 64, 2), dim3(256), 0, stream>>>(A, V, E, ws);
  k_rowstats<<<dim3(2048, 2), dim3(256), 0, stream>>>(A, V, E, ws, out);
  k_sgemm  <<<dim3(128, 2), dim3(512), 0, stream>>>(ws);
  k_sfinal <<<dim3(1), dim3(256), 0, stream>>>(ws);
  k_loss   <<<dim3(256), dim3(256), 0, stream>>>(ws);
  k_fin    <<<dim3(1), dim3(256), 0, stream>>>(ws, out);
}